// Round 4
// baseline (248.132 us; speedup 1.0000x reference)
//
#include <hip/hip_runtime.h>
#include <hip/hip_bf16.h>

#define LRELU_SLOPE 0.2f

typedef __attribute__((ext_vector_type(8))) short short8;
typedef __attribute__((ext_vector_type(4))) float float4v;

// bf16 <-> fp32 helpers (raw ushort storage)
__device__ inline float b2f(unsigned short u) {
    union { unsigned int i; float f; } v; v.i = ((unsigned int)u) << 16; return v.f;
}
__device__ inline unsigned short f2b(float f) {
    union { float f; unsigned int i; } v; v.f = f;
    unsigned int x = v.i;
    unsigned int r = x + 0x7fffu + ((x >> 16) & 1u);   // round-to-nearest-even
    return (unsigned short)(r >> 16);
}
__device__ inline float lrelu(float x) { return x > 0.f ? x : LRELU_SLOPE * x; }

// ---------------------------------------------------------------------------
// prep: zero deg[] (must complete before gemm1's atomics -> own dispatch) and
// pre-convert W1/W2 to bf16 transposed (wt layout) so both GEMMs stage
// weights as pure 16B copies (no per-block f2b, no scalar LDS writes).
// ---------------------------------------------------------------------------
__global__ __launch_bounds__(256) void prep_kernel(
        const float* __restrict__ W1, const float* __restrict__ W2,
        unsigned short* __restrict__ w1t, unsigned short* __restrict__ w2t,
        int* __restrict__ deg, int N) {
    int gid = blockIdx.x * 256 + threadIdx.x;
    int gstride = gridDim.x * 256;
    for (int i = gid; i < N; i += gstride) deg[i] = 0;
    // w1t[n*128+k] = bf16(W1[k*128+n])  (n = out col 0..127, k = in 0..127)
    for (int i = gid; i < 16384; i += gstride) {
        int n = i >> 7, k = i & 127;
        w1t[i] = f2b(W1[k * 128 + n]);
    }
    // w2t[n*128+k] = bf16(W2[k*32+n])   (n = out col 0..31, k = in 0..127)
    for (int i = gid; i < 4096; i += gstride) {
        int n = i >> 7, k = i & 127;
        w2t[i] = f2b(W2[k * 32 + n]);
    }
}

// ---------------------------------------------------------------------------
// GEMM1 (MFMA bf16) + fused dots1 + fused global deg count.
// W staged via uint4 copies of prepacked w1t (writes are 16B/lane across
// consecutive 256B LDS spans -> conflict-free; unlike R1's float4 variant
// whose 4-row scalar writes hit 2 banks).
// ---------------------------------------------------------------------------
__global__ __launch_bounds__(256) void gemm1_mfma_kernel(
        const float* __restrict__ x, const unsigned short* __restrict__ w1t,
        const float* __restrict__ a_src, const float* __restrict__ a_dst,
        unsigned short* __restrict__ h1b, float* __restrict__ es,
        float* __restrict__ ed, int N,
        const int* __restrict__ dst, int E, int Etot,
        int* __restrict__ deg) {
    __shared__ unsigned short xs[64][136];
    __shared__ unsigned short wt[128][136];
    int tid = threadIdx.x;
    int n0 = blockIdx.x * 64;

    {   // W1 stage: 8 x (uint4 load + ds_write_b128) per thread
        const uint4* wv = (const uint4*)w1t;
        for (int i = tid; i < 2048; i += 256) {
            int n = i >> 4, k8 = i & 15;
            *(uint4*)&wt[n][k8 * 8] = wv[i];
        }
    }
    {
        int rows = N - n0; if (rows > 64) rows = 64;
        const float4* xv = (const float4*)(x + (size_t)n0 * 128);
        int lim = rows * 32;                 // float4 count
        for (int i = tid; i < lim; i += 256) {
            float4 v = xv[i];
            int r = i >> 5, c4 = (i & 31) << 2;
            uint2 p;
            p.x = (unsigned int)f2b(v.x) | ((unsigned int)f2b(v.y) << 16);
            p.y = (unsigned int)f2b(v.z) | ((unsigned int)f2b(v.w) << 16);
            *(uint2*)&xs[r][c4] = p;
        }
    }
    __syncthreads();

    int wave = tid >> 6;
    int lane = tid & 63;
    int lrow = lane & 15;
    int quad = lane >> 4;

    short8 afr[4];
#pragma unroll
    for (int kc = 0; kc < 4; kc++)
        afr[kc] = *(const short8*)&xs[wave * 16 + lrow][kc * 32 + quad * 8];
    __syncthreads();   // all waves' A-fragment reads done before xs is reused

#pragma unroll
    for (int ct = 0; ct < 8; ct++) {
        float4v acc = {0.f, 0.f, 0.f, 0.f};
#pragma unroll
        for (int kc = 0; kc < 4; kc++) {
            short8 bfr = *(const short8*)&wt[ct * 16 + lrow][kc * 32 + quad * 8];
            acc = __builtin_amdgcn_mfma_f32_16x16x32_bf16(afr[kc], bfr, acc, 0, 0, 0);
        }
#pragma unroll
        for (int r = 0; r < 4; r++) {
            int lr = wave * 16 + quad * 4 + r;
            int grow = n0 + lr;
            unsigned short hb = f2b(acc[r]);
            xs[lr][ct * 16 + lrow] = hb;           // stage result tile for dots
            if (grow < N)
                h1b[grow * 128 + ct * 16 + lrow] = hb;
        }
    }
    __syncthreads();   // xs result tile ready

    // fused dots1: thread = (row, head); 32-channel dot per head
    int row = tid >> 2, h = tid & 3;
    int rg = n0 + row;
    if (rg < N) {
        const float* ap = a_src + h * 32;
        const float* bp = a_dst + h * 32;
        float s = 0.f, d = 0.f;
#pragma unroll
        for (int c2 = 0; c2 < 16; c2++) {
            unsigned int u = *(const unsigned int*)&xs[row][h * 32 + 2 * c2];
            float v0 = b2f((unsigned short)(u & 0xffffu));
            float v1 = b2f((unsigned short)(u >> 16));
            float2 a = *(const float2*)&ap[2 * c2];
            float2 b = *(const float2*)&bp[2 * c2];
            s += v0 * a.x + v1 * a.y;
            d += v0 * b.x + v1 * b.y;
        }
        es[rg * 4 + h] = s;
        ed[rg * 4 + h] = d;
    }

    // fused deg count: fire-and-forget global atomics (no return -> no wait).
    // ~17 hits per address over 50K addresses: negligible contention.
    int gid = blockIdx.x * 256 + tid;
    int gstride = gridDim.x * 256;
    for (int i = gid; i < Etot; i += gstride) {
        int d = (i < E) ? dst[i] : (i - E);
        atomicAdd(&deg[d], 1);
    }
}

// ---------------------------------------------------------------------------
// scanP1: tile-exclusive scan of deg[0..N) (49 tiles of 1024). Writes the
// exclusive prefix to BOTH cur (running counters for place's atomics) and
// loc (read-only copy for ptr derivation); psum[tile] = inclusive total.
// 4x smaller than the old scanA (50K vs 200K elements).
// ---------------------------------------------------------------------------
__global__ __launch_bounds__(1024) void scanP1_kernel(
        int* __restrict__ cur, int* __restrict__ loc,
        int* __restrict__ psum, int M) {
    __shared__ int tile[1024];
    int i = blockIdx.x * 1024 + threadIdx.x;
    int v = (i < M) ? cur[i] : 0;
    tile[threadIdx.x] = v;
    __syncthreads();
    for (int off = 1; off < 1024; off <<= 1) {
        int t = (threadIdx.x >= (unsigned)off) ? tile[threadIdx.x - off] : 0;
        __syncthreads();
        tile[threadIdx.x] += t;
        __syncthreads();
    }
    int incl = tile[threadIdx.x];
    int excl = incl - v;
    if (i < M) { cur[i] = excl; loc[i] = excl; }
    if (threadIdx.x == 1023) psum[blockIdx.x] = incl;
}

// Inline exclusive scan of psum[0..nt) into boffl (256 threads, ~16 barriers).
__device__ inline void boff_scan(const int* __restrict__ psum, int nt,
                                 int* boffl, int tid) {
    int v = (tid < nt) ? psum[tid] : 0;
    boffl[tid] = v;
    __syncthreads();
    for (int off = 1; off < 256; off <<= 1) {
        int t = (tid >= off) ? boffl[tid - off] : 0;
        __syncthreads();
        boffl[tid] += t;
        __syncthreads();
    }
    int excl = boffl[tid] - v;
    __syncthreads();
    boffl[tid] = excl;
    __syncthreads();
}

// ---------------------------------------------------------------------------
// place: replaces partition+finalize. One pass over edges: final CSR position
// via boff + global atomicAdd on per-node cur (started at tile-local prefix
// by scanP1); writes csr_src + fp16 edge weights; first N+1 threads also
// derive+write ptr[] from loc. No bkt roundtrip (-10MB), one fewer dispatch.
// ---------------------------------------------------------------------------
__global__ __launch_bounds__(256) void place_kernel(
        const int* __restrict__ src, const int* __restrict__ dst,
        int E, int Etot, int N,
        const int* __restrict__ loc, const int* __restrict__ psum, int nt,
        int* __restrict__ cur,
        const float* __restrict__ es, const float* __restrict__ ed,
        int* __restrict__ ptr, int* __restrict__ csr_src,
        _Float16* __restrict__ w1h) {
    __shared__ int boffl[256];
    int tid = threadIdx.x;
    boff_scan(psum, nt, boffl, tid);
    int gid = blockIdx.x * 256 + tid;
    if (gid <= N)
        ptr[gid] = (gid < N) ? (loc[gid] + boffl[gid >> 10]) : Etot;
    if (gid < Etot) {
        int s, d;
        if (gid < E) { s = src[gid]; d = dst[gid]; }
        else         { s = d = gid - E; }
        int pos = boffl[d >> 10] + atomicAdd(&cur[d], 1);
        csr_src[pos] = s;
        float4 a = *(const float4*)&es[s * 4];
        float4 bb = *(const float4*)&ed[d * 4];
        union { _Float16 h[4]; uint2 u; } ww;
        ww.h[0] = (_Float16)__expf(lrelu(a.x + bb.x));
        ww.h[1] = (_Float16)__expf(lrelu(a.y + bb.y));
        ww.h[2] = (_Float16)__expf(lrelu(a.z + bb.z));
        ww.h[3] = (_Float16)__expf(lrelu(a.w + bb.w));
        *(uint2*)&w1h[(size_t)pos * 4] = ww.u;
    }
}

// ---------------------------------------------------------------------------
// GEMM2 (MFMA bf16) + fused dots2; W2 staged from prepacked w2t.
// ---------------------------------------------------------------------------
__global__ __launch_bounds__(256) void gemm2_mfma_kernel(
        const unsigned short* __restrict__ h1e, const unsigned short* __restrict__ w2t,
        const float* __restrict__ a_src, const float* __restrict__ a_dst,
        unsigned short* __restrict__ h2b, float* __restrict__ es,
        float* __restrict__ ed, int N) {
    __shared__ unsigned short xs[64][136];
    __shared__ unsigned short wt[32][136];
    int tid = threadIdx.x;
    int n0 = blockIdx.x * 64;

    {   // W2 stage: 2 x (uint4 load + ds_write_b128) per thread
        const uint4* wv = (const uint4*)w2t;
        for (int i = tid; i < 512; i += 256) {
            int n = i >> 4, k8 = i & 15;
            *(uint4*)&wt[n][k8 * 8] = wv[i];
        }
    }
    {
        const unsigned int* srcp = (const unsigned int*)(h1e + (size_t)n0 * 128);
        int rows = (N - n0) < 64 ? (N - n0) : 64;
        int maxu = rows * 64;
        for (int i = tid; i < 4096; i += 256) {
            unsigned int v = (i < maxu) ? srcp[i] : 0u;
            int r = i >> 6, cp = (i & 63) << 1;
            *(unsigned int*)&xs[r][cp] = v;
        }
    }
    __syncthreads();

    int wave = tid >> 6;
    int lane = tid & 63;
    int lrow = lane & 15;
    int quad = lane >> 4;

    short8 afr[4];
#pragma unroll
    for (int kc = 0; kc < 4; kc++)
        afr[kc] = *(const short8*)&xs[wave * 16 + lrow][kc * 32 + quad * 8];
    __syncthreads();

#pragma unroll
    for (int ct = 0; ct < 2; ct++) {
        float4v acc = {0.f, 0.f, 0.f, 0.f};
#pragma unroll
        for (int kc = 0; kc < 4; kc++) {
            short8 bfr = *(const short8*)&wt[ct * 16 + lrow][kc * 32 + quad * 8];
            acc = __builtin_amdgcn_mfma_f32_16x16x32_bf16(afr[kc], bfr, acc, 0, 0, 0);
        }
#pragma unroll
        for (int r = 0; r < 4; r++) {
            int lr = wave * 16 + quad * 4 + r;
            int grow = n0 + lr;
            unsigned short hb = f2b(acc[r]);
            xs[lr][ct * 16 + lrow] = hb;
            if (grow < N)
                h2b[(size_t)grow * 32 + ct * 16 + lrow] = hb;
        }
    }
    __syncthreads();

    // fused dots2 (1 head, 32 channels): threads 0..63 = rows
    if (tid < 64) {
        int rg = n0 + tid;
        if (rg < N) {
            float s = 0.f, d = 0.f;
#pragma unroll
            for (int c2 = 0; c2 < 16; c2++) {
                unsigned int u = *(const unsigned int*)&xs[tid][2 * c2];
                float v0 = b2f((unsigned short)(u & 0xffffu));
                float v1 = b2f((unsigned short)(u >> 16));
                float2 a = *(const float2*)&a_src[2 * c2];
                float2 b = *(const float2*)&a_dst[2 * c2];
                s += v0 * a.x + v1 * a.y;
                d += v0 * b.x + v1 * b.y;
            }
            es[rg] = s;
            ed[rg] = d;
        }
    }
}

// ---------------------------------------------------------------------------
// Aggregation layer 1: R0-exact proven layout — 16 lanes/node x 8 channels,
// 4 nodes/wave, 16/block; linear fp16 weight stream. (R1 1-node/wave and
// R2 index-prefetch both regressed: loop is TLP-saturated.)
// ---------------------------------------------------------------------------
__global__ __launch_bounds__(256) void agg1_kernel(
        const uint4* __restrict__ h1v, const _Float16* __restrict__ w1h,
        const int* __restrict__ csr, const int* __restrict__ ptr,
        const float* __restrict__ b1, uint4* __restrict__ h1e_v, int N) {
    int tid = threadIdx.x;
    int n = blockIdx.x * 16 + (tid >> 4);
    if (n >= N) return;
    int cl = tid & 15;           // 16-B granule: channels 8cl..8cl+7
    int h = cl >> 2;             // head
    int start = ptr[n], end = ptr[n + 1];
    float a0 = 0.f, a1 = 0.f, a2 = 0.f, a3 = 0.f;
    float a4 = 0.f, a5 = 0.f, a6 = 0.f, a7 = 0.f, ws = 0.f;
    int i = start;
    for (; i + 4 <= end; i += 4) {
        int s[4]; float v[4]; uint4 g[4];
#pragma unroll
        for (int k = 0; k < 4; k++) s[k] = csr[i + k];
#pragma unroll
        for (int k = 0; k < 4; k++) v[k] = (float)w1h[(size_t)(i + k) * 4 + h];
#pragma unroll
        for (int k = 0; k < 4; k++) g[k] = h1v[(s[k] << 4) + cl];
#pragma unroll
        for (int k = 0; k < 4; k++) {
            a0 += v[k] * b2f((unsigned short)(g[k].x & 0xffffu));
            a1 += v[k] * b2f((unsigned short)(g[k].x >> 16));
            a2 += v[k] * b2f((unsigned short)(g[k].y & 0xffffu));
            a3 += v[k] * b2f((unsigned short)(g[k].y >> 16));
            a4 += v[k] * b2f((unsigned short)(g[k].z & 0xffffu));
            a5 += v[k] * b2f((unsigned short)(g[k].z >> 16));
            a6 += v[k] * b2f((unsigned short)(g[k].w & 0xffffu));
            a7 += v[k] * b2f((unsigned short)(g[k].w >> 16));
            ws += v[k];
        }
    }
    for (; i < end; i++) {
        int s = csr[i];
        float v = (float)w1h[(size_t)i * 4 + h];
        uint4 g = h1v[(s << 4) + cl];
        a0 += v * b2f((unsigned short)(g.x & 0xffffu));
        a1 += v * b2f((unsigned short)(g.x >> 16));
        a2 += v * b2f((unsigned short)(g.y & 0xffffu));
        a3 += v * b2f((unsigned short)(g.y >> 16));
        a4 += v * b2f((unsigned short)(g.z & 0xffffu));
        a5 += v * b2f((unsigned short)(g.z >> 16));
        a6 += v * b2f((unsigned short)(g.w & 0xffffu));
        a7 += v * b2f((unsigned short)(g.w >> 16));
        ws += v;
    }
    float r = 1.f / ws;
    float4 bb0 = ((const float4*)b1)[cl * 2];
    float4 bb1 = ((const float4*)b1)[cl * 2 + 1];
    float o0 = a0 * r + bb0.x;
    float o1 = a1 * r + bb0.y;
    float o2 = a2 * r + bb0.z;
    float o3 = a3 * r + bb0.w;
    float o4 = a4 * r + bb1.x;
    float o5 = a5 * r + bb1.y;
    float o6 = a6 * r + bb1.z;
    float o7 = a7 * r + bb1.w;
    o0 = o0 > 0.f ? o0 : __expf(o0) - 1.f;
    o1 = o1 > 0.f ? o1 : __expf(o1) - 1.f;
    o2 = o2 > 0.f ? o2 : __expf(o2) - 1.f;
    o3 = o3 > 0.f ? o3 : __expf(o3) - 1.f;
    o4 = o4 > 0.f ? o4 : __expf(o4) - 1.f;
    o5 = o5 > 0.f ? o5 : __expf(o5) - 1.f;
    o6 = o6 > 0.f ? o6 : __expf(o6) - 1.f;
    o7 = o7 > 0.f ? o7 : __expf(o7) - 1.f;
    uint4 outv;
    outv.x = (unsigned int)f2b(o0) | ((unsigned int)f2b(o1) << 16);
    outv.y = (unsigned int)f2b(o2) | ((unsigned int)f2b(o3) << 16);
    outv.z = (unsigned int)f2b(o4) | ((unsigned int)f2b(o5) << 16);
    outv.w = (unsigned int)f2b(o6) | ((unsigned int)f2b(o7) << 16);
    h1e_v[(n << 4) + cl] = outv;
}

// ---------------------------------------------------------------------------
// Aggregation layer 2: R0-exact — 8 lanes/node x 4 channels, 8 nodes/wave,
// 32/block; unroll x8; inline exp weights.
// ---------------------------------------------------------------------------
__global__ __launch_bounds__(256) void agg2_kernel(
        const uint2* __restrict__ h2v, const float* __restrict__ es,
        const float* __restrict__ ed, const int* __restrict__ csr,
        const int* __restrict__ ptr, const float* __restrict__ b2,
        float* __restrict__ out, int N) {
    int tid = threadIdx.x;
    int n = blockIdx.x * 32 + (tid >> 3);
    if (n >= N) return;
    int cl = tid & 7;            // channels 4cl..4cl+3
    float edl = ed[n];
    int start = ptr[n], end = ptr[n + 1];
    float a0 = 0.f, a1 = 0.f, a2 = 0.f, a3 = 0.f, ws = 0.f;
    int i = start;
    for (; i + 8 <= end; i += 8) {
        int s[8]; float e[8]; uint2 g[8];
#pragma unroll
        for (int k = 0; k < 8; k++) s[k] = csr[i + k];
#pragma unroll
        for (int k = 0; k < 8; k++) e[k] = es[s[k]];
#pragma unroll
        for (int k = 0; k < 8; k++) g[k] = h2v[(s[k] << 3) + cl];
#pragma unroll
        for (int k = 0; k < 8; k++) {
            float v = __expf(lrelu(e[k] + edl));
            a0 += v * b2f((unsigned short)(g[k].x & 0xffffu));
            a1 += v * b2f((unsigned short)(g[k].x >> 16));
            a2 += v * b2f((unsigned short)(g[k].y & 0xffffu));
            a3 += v * b2f((unsigned short)(g[k].y >> 16));
            ws += v;
        }
    }
    for (; i < end; i++) {
        int s = csr[i];
        float v = __expf(lrelu(es[s] + edl));
        uint2 g = h2v[(s << 3) + cl];
        a0 += v * b2f((unsigned short)(g.x & 0xffffu));
        a1 += v * b2f((unsigned short)(g.x >> 16));
        a2 += v * b2f((unsigned short)(g.y & 0xffffu));
        a3 += v * b2f((unsigned short)(g.y >> 16));
        ws += v;
    }
    float r = 1.f / ws;
    float4 bb = ((const float4*)b2)[cl];
    float4 o;
    o.x = a0 * r + bb.x;
    o.y = a1 * r + bb.y;
    o.z = a2 * r + bb.z;
    o.w = a3 * r + bb.w;
    ((float4*)out)[(size_t)n * 8 + cl] = o;
}

// ---------------------------------------------------------------------------
extern "C" void kernel_launch(void* const* d_in, const int* in_sizes, int n_in,
                              void* d_out, int out_size, void* d_ws, size_t ws_size,
                              hipStream_t stream) {
    const float* x      = (const float*)d_in[0];
    const int*   ei     = (const int*)  d_in[1];
    const float* W1     = (const float*)d_in[2];
    const float* a_src1 = (const float*)d_in[3];
    const float* a_dst1 = (const float*)d_in[4];
    const float* b1     = (const float*)d_in[5];
    const float* W2     = (const float*)d_in[6];
    const float* a_src2 = (const float*)d_in[7];
    const float* a_dst2 = (const float*)d_in[8];
    const float* b2     = (const float*)d_in[9];
    float* outp = (float*)d_out;

    const int N = in_sizes[0] / 128;   // 50000
    const int E = in_sizes[1] / 2;     // 800000
    const int Etot = E + N;            // 850000

    const int* src = ei;
    const int* dst = ei + E;

    const int ntile = (N + 1023) / 1024;             // 49 scan tiles

    // workspace layout (bytes); max offset unchanged from R0 (~48.8 MB)
    char* w = (char*)d_ws;
    unsigned short* h1b = (unsigned short*)(w + 0);          // 12,800,000
    unsigned short* h1e = (unsigned short*)(w + 12800000);   // 12,800,000
    unsigned short* h2b = (unsigned short*)(w + 25600000);   //  3,200,000
    float* es1  = (float*)(w + 28800000);                    //    800,000
    float* ed1  = (float*)(w + 29600000);                    //    800,000
    float* es2  = (float*)(w + 30400000);                    //    200,000
    float* ed2  = (float*)(w + 30600000);                    //    200,000
    int*   ptr  = (int*)  (w + 30800000);                    //    200,064
    int*   psum = (int*)  (w + 31000064);                    //      1,024
    int*   deg  = (int*)  (w + 31001088);                    //    200,192 (also cur)
    int*   loc  = (int*)  (w + 31201280);                    //    200,000
    int*   csr_src = (int*)(w + 31801856);                   //  3,400,000
    unsigned short* w1t = (unsigned short*)(w + 35201856);   //     32,768
    unsigned short* w2t = (unsigned short*)(w + 35234624);   //      8,192
    _Float16* w1h = (_Float16*)(w + 42001856);               //  6,800,000 -> 48,801,856

    // --- prep: zero deg + prepack W1/W2 as bf16 transposed ---
    prep_kernel<<<64, 256, 0, stream>>>(W1, W2, w1t, w2t, deg, N);

    // --- Layer-1 GEMM + fused dots1 + fused deg atomics ---
    gemm1_mfma_kernel<<<(N + 63) / 64, 256, 0, stream>>>(x, w1t, a_src1, a_dst1,
                                                         h1b, es1, ed1, N,
                                                         dst, E, Etot, deg);

    // --- CSR build: scan deg -> place (ptr + csr_src + w1h in one pass) ---
    scanP1_kernel<<<ntile, 1024, 0, stream>>>(deg, loc, psum, N);
    place_kernel<<<(Etot + 255) / 256, 256, 0, stream>>>(src, dst, E, Etot, N,
                                                         loc, psum, ntile, deg,
                                                         es1, ed1, ptr, csr_src,
                                                         w1h);

    // --- Layer 1 aggregate (linear fp16 weight stream) ---
    agg1_kernel<<<(N + 15) / 16, 256, 0, stream>>>((const uint4*)h1b, w1h,
                                                   csr_src, ptr, b1,
                                                   (uint4*)h1e, N);

    // --- Layer 2: GEMM + fused dots, then aggregate with inline weights ---
    gemm2_mfma_kernel<<<(N + 63) / 64, 256, 0, stream>>>(h1e, w2t, a_src2, a_dst2,
                                                         h2b, es2, ed2, N);
    agg2_kernel<<<(N + 31) / 32, 256, 0, stream>>>((const uint2*)h2b, es2, ed2,
                                                   csr_src, ptr, b2, outp, N);
}

// Round 5
// 198.943 us; speedup vs baseline: 1.2472x; 1.2472x over previous
//
#include <hip/hip_runtime.h>
#include <hip/hip_bf16.h>

#define LRELU_SLOPE 0.2f
#define NB_SHIFT 7          // 128 dst-nodes per bucket
#define NBLK 512            // hist/partition parallel chunks

typedef __attribute__((ext_vector_type(8))) short short8;
typedef __attribute__((ext_vector_type(4))) float float4v;

// bf16 <-> fp32 helpers (raw ushort storage)
__device__ inline float b2f(unsigned short u) {
    union { unsigned int i; float f; } v; v.i = ((unsigned int)u) << 16; return v.f;
}
__device__ inline unsigned short f2b(float f) {
    union { float f; unsigned int i; } v; v.f = f;
    unsigned int x = v.i;
    unsigned int r = x + 0x7fffu + ((x >> 16) & 1u);   // round-to-nearest-even
    return (unsigned short)(r >> 16);
}
__device__ inline float lrelu(float x) { return x > 0.f ? x : LRELU_SLOPE * x; }

// ---------------------------------------------------------------------------
// GEMM1 (MFMA bf16) + fused dots1 + fused CSR hist (blocks < NBLK).
// R3 structure. R5 change: h1b written via uint4 copies from the staged xs
// tile (was 32 scalar 2B stores/thread inside the MFMA loop; waves now store
// 1KB contiguous per instr). LDS-privatized hist kept — R4 measured global
// deg atomics at +25MB write traffic / +40us (cross-XCD line ping-pong).
// ---------------------------------------------------------------------------
__global__ __launch_bounds__(256) void gemm1_mfma_kernel(
        const float* __restrict__ x, const float* __restrict__ W1,
        const float* __restrict__ a_src, const float* __restrict__ a_dst,
        unsigned short* __restrict__ h1b, float* __restrict__ es,
        float* __restrict__ ed, int N,
        const int* __restrict__ dst, int E, int Etot, int nb, int chunk,
        int* __restrict__ cnt) {
    __shared__ unsigned short xs[64][136];
    __shared__ unsigned short wt[128][136];
    int tid = threadIdx.x;
    int n0 = blockIdx.x * 64;

    for (int i = tid; i < 128 * 128; i += 256) {
        int k = i >> 7, n = i & 127;
        wt[n][k] = f2b(W1[i]);
    }
    {
        int rows = N - n0; if (rows > 64) rows = 64;
        const float4* xv = (const float4*)(x + (size_t)n0 * 128);
        int lim = rows * 32;                 // float4 count
        for (int i = tid; i < lim; i += 256) {
            float4 v = xv[i];
            int r = i >> 5, c4 = (i & 31) << 2;
            uint2 p;
            p.x = (unsigned int)f2b(v.x) | ((unsigned int)f2b(v.y) << 16);
            p.y = (unsigned int)f2b(v.z) | ((unsigned int)f2b(v.w) << 16);
            *(uint2*)&xs[r][c4] = p;
        }
    }
    __syncthreads();

    int wave = tid >> 6;
    int lane = tid & 63;
    int lrow = lane & 15;
    int quad = lane >> 4;

    short8 afr[4];
#pragma unroll
    for (int kc = 0; kc < 4; kc++)
        afr[kc] = *(const short8*)&xs[wave * 16 + lrow][kc * 32 + quad * 8];
    __syncthreads();   // all waves' A-fragment reads done before xs is reused

#pragma unroll
    for (int ct = 0; ct < 8; ct++) {
        float4v acc = {0.f, 0.f, 0.f, 0.f};
#pragma unroll
        for (int kc = 0; kc < 4; kc++) {
            short8 bfr = *(const short8*)&wt[ct * 16 + lrow][kc * 32 + quad * 8];
            acc = __builtin_amdgcn_mfma_f32_16x16x32_bf16(afr[kc], bfr, acc, 0, 0, 0);
        }
#pragma unroll
        for (int r = 0; r < 4; r++) {
            int lr = wave * 16 + quad * 4 + r;
            xs[lr][ct * 16 + lrow] = f2b(acc[r]);  // stage result tile only
        }
    }
    __syncthreads();   // xs result tile ready; wt reads done (reused below)

    {   // vectorized h1b write: rows*16 uint4 (16B/lane, 1KB/wave-instr)
        int rows = N - n0; if (rows > 64) rows = 64;
        int lim4 = rows * 16;
        for (int i = tid; i < lim4; i += 256) {
            int r = i >> 4, c8 = i & 15;
            *(uint4*)&h1b[(size_t)(n0 + r) * 128 + c8 * 8] =
                *(const uint4*)&xs[r][c8 * 8];
        }
    }

    // fused dots1: thread = (row, head); 32-channel dot per head
    int row = tid >> 2, h = tid & 3;
    int rg = n0 + row;
    if (rg < N) {
        const float* ap = a_src + h * 32;
        const float* bp = a_dst + h * 32;
        float s = 0.f, d = 0.f;
#pragma unroll
        for (int c2 = 0; c2 < 16; c2++) {
            unsigned int u = *(const unsigned int*)&xs[row][h * 32 + 2 * c2];
            float v0 = b2f((unsigned short)(u & 0xffffu));
            float v1 = b2f((unsigned short)(u >> 16));
            float2 a = *(const float2*)&ap[2 * c2];
            float2 b = *(const float2*)&bp[2 * c2];
            s += v0 * a.x + v1 * a.y;
            d += v0 * b.x + v1 * b.y;
        }
        es[rg * 4 + h] = s;
        ed[rg * 4 + h] = d;
    }

    // fused CSR histogram (reuses wt LDS; all threads hit the barriers)
    int* histm = (int*)&wt[0][0];
    int blk = blockIdx.x;
    if (blk < NBLK)
        for (int i = tid; i < nb; i += 256) histm[i] = 0;
    __syncthreads();
    if (blk < NBLK) {
        int lo = blk * chunk;
        int hi = lo + chunk; if (hi > Etot) hi = Etot;
        for (int i = lo + tid; i < hi; i += 256) {
            int d = (i < E) ? dst[i] : (i - E);
            atomicAdd(&histm[d >> NB_SHIFT], 1);
        }
    }
    __syncthreads();
    if (blk < NBLK)
        for (int b = tid; b < nb; b += 256)
            cnt[b * NBLK + blk] = histm[b];
}

// ---------------------------------------------------------------------------
// scanA: tile-exclusive scan of cnt; bsum[tile] = inclusive tile total.
// (scanB folded inline into partition/finalize — R3.)
// ---------------------------------------------------------------------------
__global__ __launch_bounds__(1024) void scanA_kernel(int* cnt, int* bsum, int M) {
    __shared__ int tile[1024];
    int i = blockIdx.x * 1024 + threadIdx.x;
    int v = (i < M) ? cnt[i] : 0;
    tile[threadIdx.x] = v;
    __syncthreads();
    for (int off = 1; off < 1024; off <<= 1) {
        int t = (threadIdx.x >= (unsigned)off) ? tile[threadIdx.x - off] : 0;
        __syncthreads();
        tile[threadIdx.x] += t;
        __syncthreads();
    }
    int incl = tile[threadIdx.x];
    if (i < M) cnt[i] = incl - v;
    if (threadIdx.x == 1023) bsum[blockIdx.x] = incl;
}

// Inline 256-slot exclusive scan of bsum[0..nbA) into boffl.
__device__ inline void boff_scan(const int* __restrict__ bsum, int nbA,
                                 int* boffl, int tid) {
    int v = (tid < nbA) ? bsum[tid] : 0;
    boffl[tid] = v;
    __syncthreads();
    for (int off = 1; off < 256; off <<= 1) {
        int t = (tid >= off) ? boffl[tid - off] : 0;
        __syncthreads();
        boffl[tid] += t;
        __syncthreads();
    }
    int excl = boffl[tid] - v;
    __syncthreads();
    boffl[tid] = excl;
    __syncthreads();
}

// ---------------------------------------------------------------------------
// CSR build, pass 2: partition edges into bucket array (LDS atomics only).
// bkt packed: (dloc<<20)|src.
// ---------------------------------------------------------------------------
__global__ __launch_bounds__(256) void partition_kernel(
        const int* __restrict__ src, const int* __restrict__ dst,
        int E, int Etot, int nb, int chunk, int nbA,
        const int* __restrict__ cnt, const int* __restrict__ bsum,
        unsigned int* __restrict__ bkt) {
    __shared__ int cur[512];
    __shared__ int boffl[256];
    int tid = threadIdx.x;
    boff_scan(bsum, nbA, boffl, tid);
    int blk = blockIdx.x;
    for (int b = tid; b < nb; b += 256) {
        int idx = b * NBLK + blk;
        cur[b] = cnt[idx] + boffl[idx >> 10];
    }
    __syncthreads();
    int lo = blk * chunk;
    int hi = lo + chunk; if (hi > Etot) hi = Etot;
    for (int i = lo + tid; i < hi; i += 256) {
        int s, d;
        if (i < E) { s = src[i]; d = dst[i]; }
        else       { s = d = i - E; }
        int pos = atomicAdd(&cur[d >> NB_SHIFT], 1);
        bkt[pos] = ((unsigned int)(d & 127) << 20) | (unsigned int)s;
    }
}

// ---------------------------------------------------------------------------
// CSR build, pass 3 (one block per bucket): degree count -> LDS scan -> ptr;
// place src indices at final CSR positions; fold in fp16 layer-1 edge weights.
// ---------------------------------------------------------------------------
__global__ __launch_bounds__(256) void finalize_kernel(
        const unsigned int* __restrict__ bkt, const int* __restrict__ cnt,
        const int* __restrict__ bsum, int nb, int nbA,
        const float* __restrict__ es, const float* __restrict__ ed,
        int* __restrict__ ptr, int* __restrict__ csr_src,
        _Float16* __restrict__ w1h, int N, int Etot) {
    __shared__ int deg[128];
    __shared__ int scn[128];
    __shared__ int cur[128];
    __shared__ int boffl[256];
    int tid = threadIdx.x;
    boff_scan(bsum, nbA, boffl, tid);
    int b = blockIdx.x;
    int idx0 = b * NBLK;
    int base = cnt[idx0] + boffl[idx0 >> 10];
    int nextbase;
    if (b + 1 < nb) {
        int idx1 = (b + 1) * NBLK;
        nextbase = cnt[idx1] + boffl[idx1 >> 10];
    } else nextbase = Etot;
    int count = nextbase - base;
    int node0 = b << NB_SHIFT;
    int nodes = N - node0; if (nodes > 128) nodes = 128;

    if (tid < 128) deg[tid] = 0;
    __syncthreads();
    for (int i = tid; i < count; i += 256)
        atomicAdd(&deg[bkt[base + i] >> 20], 1);
    __syncthreads();
    int v = (tid < 128) ? deg[tid] : 0;
    if (tid < 128) scn[tid] = v;
    __syncthreads();
    for (int off = 1; off < 128; off <<= 1) {
        int t = (tid < 128 && tid >= (unsigned)off) ? scn[tid - off] : 0;
        __syncthreads();
        if (tid < 128) scn[tid] += t;
        __syncthreads();
    }
    if (tid < 128) {
        int excl = scn[tid] - v;
        cur[tid] = excl;
        if (tid < nodes) ptr[node0 + tid] = base + excl;
    }
    if (b == nb - 1 && tid == 0) ptr[N] = Etot;
    __syncthreads();
    for (int i = tid; i < count; i += 256) {
        unsigned int p = bkt[base + i];
        int dloc = p >> 20;
        int s = (int)(p & 0xFFFFFu);
        int pos = base + atomicAdd(&cur[dloc], 1);
        csr_src[pos] = s;
        float4 a = *(const float4*)&es[s * 4];
        float4 bb = *(const float4*)&ed[(node0 + dloc) * 4];
        union { _Float16 h[4]; uint2 u; } ww;
        ww.h[0] = (_Float16)__expf(lrelu(a.x + bb.x));
        ww.h[1] = (_Float16)__expf(lrelu(a.y + bb.y));
        ww.h[2] = (_Float16)__expf(lrelu(a.z + bb.z));
        ww.h[3] = (_Float16)__expf(lrelu(a.w + bb.w));
        *(uint2*)&w1h[(size_t)pos * 4] = ww.u;
    }
}

// ---------------------------------------------------------------------------
// GEMM2 (MFMA bf16) + fused dots2. R5: vectorized h2b write from xs.
// ---------------------------------------------------------------------------
__global__ __launch_bounds__(256) void gemm2_mfma_kernel(
        const unsigned short* __restrict__ h1e, const float* __restrict__ W2,
        const float* __restrict__ a_src, const float* __restrict__ a_dst,
        unsigned short* __restrict__ h2b, float* __restrict__ es,
        float* __restrict__ ed, int N) {
    __shared__ unsigned short xs[64][136];
    __shared__ unsigned short wt[32][136];
    int tid = threadIdx.x;
    int n0 = blockIdx.x * 64;

    for (int i = tid; i < 128 * 32; i += 256) {
        int k = i >> 5, n = i & 31;
        wt[n][k] = f2b(W2[i]);
    }
    {
        const unsigned int* srcp = (const unsigned int*)(h1e + (size_t)n0 * 128);
        int rows = (N - n0) < 64 ? (N - n0) : 64;
        int maxu = rows * 64;
        for (int i = tid; i < 4096; i += 256) {
            unsigned int v = (i < maxu) ? srcp[i] : 0u;
            int r = i >> 6, cp = (i & 63) << 1;
            *(unsigned int*)&xs[r][cp] = v;
        }
    }
    __syncthreads();

    int wave = tid >> 6;
    int lane = tid & 63;
    int lrow = lane & 15;
    int quad = lane >> 4;

    short8 afr[4];
#pragma unroll
    for (int kc = 0; kc < 4; kc++)
        afr[kc] = *(const short8*)&xs[wave * 16 + lrow][kc * 32 + quad * 8];
    __syncthreads();

#pragma unroll
    for (int ct = 0; ct < 2; ct++) {
        float4v acc = {0.f, 0.f, 0.f, 0.f};
#pragma unroll
        for (int kc = 0; kc < 4; kc++) {
            short8 bfr = *(const short8*)&wt[ct * 16 + lrow][kc * 32 + quad * 8];
            acc = __builtin_amdgcn_mfma_f32_16x16x32_bf16(afr[kc], bfr, acc, 0, 0, 0);
        }
#pragma unroll
        for (int r = 0; r < 4; r++) {
            int lr = wave * 16 + quad * 4 + r;
            xs[lr][ct * 16 + lrow] = f2b(acc[r]);
        }
    }
    __syncthreads();

    {   // vectorized h2b write: rows*4 uint4
        int rows = (N - n0) < 64 ? (N - n0) : 64;
        int lim4 = rows * 4;
        for (int i = tid; i < lim4; i += 256) {
            int r = i >> 2, c8 = i & 3;
            *(uint4*)&h2b[(size_t)(n0 + r) * 32 + c8 * 8] =
                *(const uint4*)&xs[r][c8 * 8];
        }
    }

    // fused dots2 (1 head, 32 channels): threads 0..63 = rows
    if (tid < 64) {
        int rg = n0 + tid;
        if (rg < N) {
            float s = 0.f, d = 0.f;
#pragma unroll
            for (int c2 = 0; c2 < 16; c2++) {
                unsigned int u = *(const unsigned int*)&xs[tid][2 * c2];
                float v0 = b2f((unsigned short)(u & 0xffffu));
                float v1 = b2f((unsigned short)(u >> 16));
                float2 a = *(const float2*)&a_src[2 * c2];
                float2 b = *(const float2*)&a_dst[2 * c2];
                s += v0 * a.x + v1 * a.y;
                d += v0 * b.x + v1 * b.y;
            }
            es[rg] = s;
            ed[rg] = d;
        }
    }
}

// ---------------------------------------------------------------------------
// Aggregation layer 1: R0-exact proven layout — 16 lanes/node x 8 channels,
// 4 nodes/wave, 16/block; linear fp16 weight stream.
// ---------------------------------------------------------------------------
__global__ __launch_bounds__(256) void agg1_kernel(
        const uint4* __restrict__ h1v, const _Float16* __restrict__ w1h,
        const int* __restrict__ csr, const int* __restrict__ ptr,
        const float* __restrict__ b1, uint4* __restrict__ h1e_v, int N) {
    int tid = threadIdx.x;
    int n = blockIdx.x * 16 + (tid >> 4);
    if (n >= N) return;
    int cl = tid & 15;           // 16-B granule: channels 8cl..8cl+7
    int h = cl >> 2;             // head
    int start = ptr[n], end = ptr[n + 1];
    float a0 = 0.f, a1 = 0.f, a2 = 0.f, a3 = 0.f;
    float a4 = 0.f, a5 = 0.f, a6 = 0.f, a7 = 0.f, ws = 0.f;
    int i = start;
    for (; i + 4 <= end; i += 4) {
        int s[4]; float v[4]; uint4 g[4];
#pragma unroll
        for (int k = 0; k < 4; k++) s[k] = csr[i + k];
#pragma unroll
        for (int k = 0; k < 4; k++) v[k] = (float)w1h[(size_t)(i + k) * 4 + h];
#pragma unroll
        for (int k = 0; k < 4; k++) g[k] = h1v[(s[k] << 4) + cl];
#pragma unroll
        for (int k = 0; k < 4; k++) {
            a0 += v[k] * b2f((unsigned short)(g[k].x & 0xffffu));
            a1 += v[k] * b2f((unsigned short)(g[k].x >> 16));
            a2 += v[k] * b2f((unsigned short)(g[k].y & 0xffffu));
            a3 += v[k] * b2f((unsigned short)(g[k].y >> 16));
            a4 += v[k] * b2f((unsigned short)(g[k].z & 0xffffu));
            a5 += v[k] * b2f((unsigned short)(g[k].z >> 16));
            a6 += v[k] * b2f((unsigned short)(g[k].w & 0xffffu));
            a7 += v[k] * b2f((unsigned short)(g[k].w >> 16));
            ws += v[k];
        }
    }
    for (; i < end; i++) {
        int s = csr[i];
        float v = (float)w1h[(size_t)i * 4 + h];
        uint4 g = h1v[(s << 4) + cl];
        a0 += v * b2f((unsigned short)(g.x & 0xffffu));
        a1 += v * b2f((unsigned short)(g.x >> 16));
        a2 += v * b2f((unsigned short)(g.y & 0xffffu));
        a3 += v * b2f((unsigned short)(g.y >> 16));
        a4 += v * b2f((unsigned short)(g.z & 0xffffu));
        a5 += v * b2f((unsigned short)(g.z >> 16));
        a6 += v * b2f((unsigned short)(g.w & 0xffffu));
        a7 += v * b2f((unsigned short)(g.w >> 16));
        ws += v;
    }
    float r = 1.f / ws;
    float4 bb0 = ((const float4*)b1)[cl * 2];
    float4 bb1 = ((const float4*)b1)[cl * 2 + 1];
    float o0 = a0 * r + bb0.x;
    float o1 = a1 * r + bb0.y;
    float o2 = a2 * r + bb0.z;
    float o3 = a3 * r + bb0.w;
    float o4 = a4 * r + bb1.x;
    float o5 = a5 * r + bb1.y;
    float o6 = a6 * r + bb1.z;
    float o7 = a7 * r + bb1.w;
    o0 = o0 > 0.f ? o0 : __expf(o0) - 1.f;
    o1 = o1 > 0.f ? o1 : __expf(o1) - 1.f;
    o2 = o2 > 0.f ? o2 : __expf(o2) - 1.f;
    o3 = o3 > 0.f ? o3 : __expf(o3) - 1.f;
    o4 = o4 > 0.f ? o4 : __expf(o4) - 1.f;
    o5 = o5 > 0.f ? o5 : __expf(o5) - 1.f;
    o6 = o6 > 0.f ? o6 : __expf(o6) - 1.f;
    o7 = o7 > 0.f ? o7 : __expf(o7) - 1.f;
    uint4 outv;
    outv.x = (unsigned int)f2b(o0) | ((unsigned int)f2b(o1) << 16);
    outv.y = (unsigned int)f2b(o2) | ((unsigned int)f2b(o3) << 16);
    outv.z = (unsigned int)f2b(o4) | ((unsigned int)f2b(o5) << 16);
    outv.w = (unsigned int)f2b(o6) | ((unsigned int)f2b(o7) << 16);
    h1e_v[(n << 4) + cl] = outv;
}

// ---------------------------------------------------------------------------
// Aggregation layer 2: R0-exact — 8 lanes/node x 4 channels, 8 nodes/wave,
// 32/block; unroll x8; inline exp weights.
// ---------------------------------------------------------------------------
__global__ __launch_bounds__(256) void agg2_kernel(
        const uint2* __restrict__ h2v, const float* __restrict__ es,
        const float* __restrict__ ed, const int* __restrict__ csr,
        const int* __restrict__ ptr, const float* __restrict__ b2,
        float* __restrict__ out, int N) {
    int tid = threadIdx.x;
    int n = blockIdx.x * 32 + (tid >> 3);
    if (n >= N) return;
    int cl = tid & 7;            // channels 4cl..4cl+3
    float edl = ed[n];
    int start = ptr[n], end = ptr[n + 1];
    float a0 = 0.f, a1 = 0.f, a2 = 0.f, a3 = 0.f, ws = 0.f;
    int i = start;
    for (; i + 8 <= end; i += 8) {
        int s[8]; float e[8]; uint2 g[8];
#pragma unroll
        for (int k = 0; k < 8; k++) s[k] = csr[i + k];
#pragma unroll
        for (int k = 0; k < 8; k++) e[k] = es[s[k]];
#pragma unroll
        for (int k = 0; k < 8; k++) g[k] = h2v[(s[k] << 3) + cl];
#pragma unroll
        for (int k = 0; k < 8; k++) {
            float v = __expf(lrelu(e[k] + edl));
            a0 += v * b2f((unsigned short)(g[k].x & 0xffffu));
            a1 += v * b2f((unsigned short)(g[k].x >> 16));
            a2 += v * b2f((unsigned short)(g[k].y & 0xffffu));
            a3 += v * b2f((unsigned short)(g[k].y >> 16));
            ws += v;
        }
    }
    for (; i < end; i++) {
        int s = csr[i];
        float v = __expf(lrelu(es[s] + edl));
        uint2 g = h2v[(s << 3) + cl];
        a0 += v * b2f((unsigned short)(g.x & 0xffffu));
        a1 += v * b2f((unsigned short)(g.x >> 16));
        a2 += v * b2f((unsigned short)(g.y & 0xffffu));
        a3 += v * b2f((unsigned short)(g.y >> 16));
        ws += v;
    }
    float r = 1.f / ws;
    float4 bb = ((const float4*)b2)[cl];
    float4 o;
    o.x = a0 * r + bb.x;
    o.y = a1 * r + bb.y;
    o.z = a2 * r + bb.z;
    o.w = a3 * r + bb.w;
    ((float4*)out)[(size_t)n * 8 + cl] = o;
}

// ---------------------------------------------------------------------------
extern "C" void kernel_launch(void* const* d_in, const int* in_sizes, int n_in,
                              void* d_out, int out_size, void* d_ws, size_t ws_size,
                              hipStream_t stream) {
    const float* x      = (const float*)d_in[0];
    const int*   ei     = (const int*)  d_in[1];
    const float* W1     = (const float*)d_in[2];
    const float* a_src1 = (const float*)d_in[3];
    const float* a_dst1 = (const float*)d_in[4];
    const float* b1     = (const float*)d_in[5];
    const float* W2     = (const float*)d_in[6];
    const float* a_src2 = (const float*)d_in[7];
    const float* a_dst2 = (const float*)d_in[8];
    const float* b2     = (const float*)d_in[9];
    float* outp = (float*)d_out;

    const int N = in_sizes[0] / 128;   // 50000
    const int E = in_sizes[1] / 2;     // 800000
    const int Etot = E + N;            // 850000

    const int* src = ei;
    const int* dst = ei + E;

    const int nb    = (N + 127) >> 7;                // 391 buckets
    const int chunk = (Etot + NBLK - 1) / NBLK;      // 1661
    const int M = nb * NBLK;                         // 200192 scan elements
    const int nbA = (M + 1023) / 1024;               // 196

    // workspace layout (bytes); ~48.8 MB
    char* w = (char*)d_ws;
    unsigned short* h1b = (unsigned short*)(w + 0);          // 12,800,000
    unsigned short* h1e = (unsigned short*)(w + 12800000);   // 12,800,000
    unsigned short* h2b = (unsigned short*)(w + 25600000);   //  3,200,000
    float* es1  = (float*)(w + 28800000);                    //    800,000
    float* ed1  = (float*)(w + 29600000);                    //    800,000
    float* es2  = (float*)(w + 30400000);                    //    200,000
    float* ed2  = (float*)(w + 30600000);                    //    200,000
    int*   ptr  = (int*)  (w + 30800000);                    //    200,064
    int*   bsum = (int*)  (w + 31000064);                    //      1,024
    int*   cnt  = (int*)  (w + 31001088);                    //    800,768
    int*   csr_src = (int*)(w + 31801856);                   //  3,400,000
    unsigned int* bkt = (unsigned int*)(w + 35201856);       //  3,400,000 (packed)
    _Float16* w1h = (_Float16*)(w + 42001856);               //  6,800,000 -> 48,801,856

    // --- Layer-1 GEMM + fused dots1 + fused hist ---
    gemm1_mfma_kernel<<<(N + 63) / 64, 256, 0, stream>>>(x, W1, a_src1, a_dst1,
                                                         h1b, es1, ed1, N,
                                                         dst, E, Etot, nb, chunk,
                                                         cnt);

    // --- CSR build: scanA -> partition -> finalize (scanB folded inline) ---
    scanA_kernel<<<nbA, 1024, 0, stream>>>(cnt, bsum, M);
    partition_kernel<<<NBLK, 256, 0, stream>>>(src, dst, E, Etot, nb, chunk, nbA,
                                               cnt, bsum, bkt);
    finalize_kernel<<<nb, 256, 0, stream>>>(bkt, cnt, bsum, nb, nbA, es1, ed1,
                                            ptr, csr_src, w1h, N, Etot);

    // --- Layer 1 aggregate (linear fp16 weight stream) ---
    agg1_kernel<<<(N + 15) / 16, 256, 0, stream>>>((const uint4*)h1b, w1h,
                                                   csr_src, ptr, b1,
                                                   (uint4*)h1e, N);

    // --- Layer 2: GEMM + fused dots, then aggregate with inline weights ---
    gemm2_mfma_kernel<<<(N + 63) / 64, 256, 0, stream>>>(h1e, W2, a_src2, a_dst2,
                                                         h2b, es2, ed2, N);
    agg2_kernel<<<(N + 31) / 32, 256, 0, stream>>>((const uint2*)h2b, es2, ed2,
                                                   csr_src, ptr, b2, outp, N);
}

// Round 6
// 197.981 us; speedup vs baseline: 1.2533x; 1.0049x over previous
//
#include <hip/hip_runtime.h>
#include <hip/hip_bf16.h>

#define LRELU_SLOPE 0.2f
#define NB_SHIFT 7          // 128 dst-nodes per bucket
#define NBLK 512            // hist/partition parallel chunks

typedef __attribute__((ext_vector_type(8))) short short8;
typedef __attribute__((ext_vector_type(4))) float float4v;

// bf16 <-> fp32 helpers (raw ushort storage)
__device__ inline float b2f(unsigned short u) {
    union { unsigned int i; float f; } v; v.i = ((unsigned int)u) << 16; return v.f;
}
__device__ inline unsigned short f2b(float f) {
    union { float f; unsigned int i; } v; v.f = f;
    unsigned int x = v.i;
    unsigned int r = x + 0x7fffu + ((x >> 16) & 1u);   // round-to-nearest-even
    return (unsigned short)(r >> 16);
}
__device__ inline float lrelu(float x) { return x > 0.f ? x : LRELU_SLOPE * x; }

// ---------------------------------------------------------------------------
// GEMM1 (MFMA bf16) + fused dots1 + fused CSR hist (blocks < NBLK).
// R5 form (vectorized h1b write; LDS-privatized hist — R4 measured global
// deg atomics at +25MB write traffic / cross-XCD line ping-pong).
// ---------------------------------------------------------------------------
__global__ __launch_bounds__(256) void gemm1_mfma_kernel(
        const float* __restrict__ x, const float* __restrict__ W1,
        const float* __restrict__ a_src, const float* __restrict__ a_dst,
        unsigned short* __restrict__ h1b, float* __restrict__ es,
        float* __restrict__ ed, int N,
        const int* __restrict__ dst, int E, int Etot, int nb, int chunk,
        int* __restrict__ cnt) {
    __shared__ unsigned short xs[64][136];
    __shared__ unsigned short wt[128][136];
    int tid = threadIdx.x;
    int n0 = blockIdx.x * 64;

    for (int i = tid; i < 128 * 128; i += 256) {
        int k = i >> 7, n = i & 127;
        wt[n][k] = f2b(W1[i]);
    }
    {
        int rows = N - n0; if (rows > 64) rows = 64;
        const float4* xv = (const float4*)(x + (size_t)n0 * 128);
        int lim = rows * 32;                 // float4 count
        for (int i = tid; i < lim; i += 256) {
            float4 v = xv[i];
            int r = i >> 5, c4 = (i & 31) << 2;
            uint2 p;
            p.x = (unsigned int)f2b(v.x) | ((unsigned int)f2b(v.y) << 16);
            p.y = (unsigned int)f2b(v.z) | ((unsigned int)f2b(v.w) << 16);
            *(uint2*)&xs[r][c4] = p;
        }
    }
    __syncthreads();

    int wave = tid >> 6;
    int lane = tid & 63;
    int lrow = lane & 15;
    int quad = lane >> 4;

    short8 afr[4];
#pragma unroll
    for (int kc = 0; kc < 4; kc++)
        afr[kc] = *(const short8*)&xs[wave * 16 + lrow][kc * 32 + quad * 8];
    __syncthreads();   // all waves' A-fragment reads done before xs is reused

#pragma unroll
    for (int ct = 0; ct < 8; ct++) {
        float4v acc = {0.f, 0.f, 0.f, 0.f};
#pragma unroll
        for (int kc = 0; kc < 4; kc++) {
            short8 bfr = *(const short8*)&wt[ct * 16 + lrow][kc * 32 + quad * 8];
            acc = __builtin_amdgcn_mfma_f32_16x16x32_bf16(afr[kc], bfr, acc, 0, 0, 0);
        }
#pragma unroll
        for (int r = 0; r < 4; r++) {
            int lr = wave * 16 + quad * 4 + r;
            xs[lr][ct * 16 + lrow] = f2b(acc[r]);  // stage result tile only
        }
    }
    __syncthreads();   // xs result tile ready; wt reads done (reused below)

    {   // vectorized h1b write: rows*16 uint4 (16B/lane, 1KB/wave-instr)
        int rows = N - n0; if (rows > 64) rows = 64;
        int lim4 = rows * 16;
        for (int i = tid; i < lim4; i += 256) {
            int r = i >> 4, c8 = i & 15;
            *(uint4*)&h1b[(size_t)(n0 + r) * 128 + c8 * 8] =
                *(const uint4*)&xs[r][c8 * 8];
        }
    }

    // fused dots1: thread = (row, head); 32-channel dot per head
    int row = tid >> 2, h = tid & 3;
    int rg = n0 + row;
    if (rg < N) {
        const float* ap = a_src + h * 32;
        const float* bp = a_dst + h * 32;
        float s = 0.f, d = 0.f;
#pragma unroll
        for (int c2 = 0; c2 < 16; c2++) {
            unsigned int u = *(const unsigned int*)&xs[row][h * 32 + 2 * c2];
            float v0 = b2f((unsigned short)(u & 0xffffu));
            float v1 = b2f((unsigned short)(u >> 16));
            float2 a = *(const float2*)&ap[2 * c2];
            float2 b = *(const float2*)&bp[2 * c2];
            s += v0 * a.x + v1 * a.y;
            d += v0 * b.x + v1 * b.y;
        }
        es[rg * 4 + h] = s;
        ed[rg * 4 + h] = d;
    }

    // fused CSR histogram (reuses wt LDS; all threads hit the barriers)
    int* histm = (int*)&wt[0][0];
    int blk = blockIdx.x;
    if (blk < NBLK)
        for (int i = tid; i < nb; i += 256) histm[i] = 0;
    __syncthreads();
    if (blk < NBLK) {
        int lo = blk * chunk;
        int hi = lo + chunk; if (hi > Etot) hi = Etot;
        for (int i = lo + tid; i < hi; i += 256) {
            int d = (i < E) ? dst[i] : (i - E);
            atomicAdd(&histm[d >> NB_SHIFT], 1);
        }
    }
    __syncthreads();
    if (blk < NBLK)
        for (int b = tid; b < nb; b += 256)
            cnt[b * NBLK + blk] = histm[b];
}

// ---------------------------------------------------------------------------
// scanA: tile-exclusive scan of cnt; bsum[tile] = inclusive tile total.
// ---------------------------------------------------------------------------
__global__ __launch_bounds__(1024) void scanA_kernel(int* cnt, int* bsum, int M) {
    __shared__ int tile[1024];
    int i = blockIdx.x * 1024 + threadIdx.x;
    int v = (i < M) ? cnt[i] : 0;
    tile[threadIdx.x] = v;
    __syncthreads();
    for (int off = 1; off < 1024; off <<= 1) {
        int t = (threadIdx.x >= (unsigned)off) ? tile[threadIdx.x - off] : 0;
        __syncthreads();
        tile[threadIdx.x] += t;
        __syncthreads();
    }
    int incl = tile[threadIdx.x];
    if (i < M) cnt[i] = incl - v;
    if (threadIdx.x == 1023) bsum[blockIdx.x] = incl;
}

// Inline 256-slot exclusive scan of bsum[0..nbA) into boffl.
__device__ inline void boff_scan(const int* __restrict__ bsum, int nbA,
                                 int* boffl, int tid) {
    int v = (tid < nbA) ? bsum[tid] : 0;
    boffl[tid] = v;
    __syncthreads();
    for (int off = 1; off < 256; off <<= 1) {
        int t = (tid >= off) ? boffl[tid - off] : 0;
        __syncthreads();
        boffl[tid] += t;
        __syncthreads();
    }
    int excl = boffl[tid] - v;
    __syncthreads();
    boffl[tid] = excl;
    __syncthreads();
}

// ---------------------------------------------------------------------------
// CSR build, pass 2: partition edges into bucket array (LDS atomics only).
// bkt packed: (dloc<<20)|src.
// ---------------------------------------------------------------------------
__global__ __launch_bounds__(256) void partition_kernel(
        const int* __restrict__ src, const int* __restrict__ dst,
        int E, int Etot, int nb, int chunk, int nbA,
        const int* __restrict__ cnt, const int* __restrict__ bsum,
        unsigned int* __restrict__ bkt) {
    __shared__ int cur[512];
    __shared__ int boffl[256];
    int tid = threadIdx.x;
    boff_scan(bsum, nbA, boffl, tid);
    int blk = blockIdx.x;
    for (int b = tid; b < nb; b += 256) {
        int idx = b * NBLK + blk;
        cur[b] = cnt[idx] + boffl[idx >> 10];
    }
    __syncthreads();
    int lo = blk * chunk;
    int hi = lo + chunk; if (hi > Etot) hi = Etot;
    for (int i = lo + tid; i < hi; i += 256) {
        int s, d;
        if (i < E) { s = src[i]; d = dst[i]; }
        else       { s = d = i - E; }
        int pos = atomicAdd(&cur[d >> NB_SHIFT], 1);
        bkt[pos] = ((unsigned int)(d & 127) << 20) | (unsigned int)s;
    }
}

// ---------------------------------------------------------------------------
// CSR build, pass 3 (one block per bucket): degree count -> LDS scan -> ptr;
// place src indices at final CSR positions; fold in fp16 layer-1 edge weights.
// ---------------------------------------------------------------------------
__global__ __launch_bounds__(256) void finalize_kernel(
        const unsigned int* __restrict__ bkt, const int* __restrict__ cnt,
        const int* __restrict__ bsum, int nb, int nbA,
        const float* __restrict__ es, const float* __restrict__ ed,
        int* __restrict__ ptr, int* __restrict__ csr_src,
        _Float16* __restrict__ w1h, int N, int Etot) {
    __shared__ int deg[128];
    __shared__ int scn[128];
    __shared__ int cur[128];
    __shared__ int boffl[256];
    int tid = threadIdx.x;
    boff_scan(bsum, nbA, boffl, tid);
    int b = blockIdx.x;
    int idx0 = b * NBLK;
    int base = cnt[idx0] + boffl[idx0 >> 10];
    int nextbase;
    if (b + 1 < nb) {
        int idx1 = (b + 1) * NBLK;
        nextbase = cnt[idx1] + boffl[idx1 >> 10];
    } else nextbase = Etot;
    int count = nextbase - base;
    int node0 = b << NB_SHIFT;
    int nodes = N - node0; if (nodes > 128) nodes = 128;

    if (tid < 128) deg[tid] = 0;
    __syncthreads();
    for (int i = tid; i < count; i += 256)
        atomicAdd(&deg[bkt[base + i] >> 20], 1);
    __syncthreads();
    int v = (tid < 128) ? deg[tid] : 0;
    if (tid < 128) scn[tid] = v;
    __syncthreads();
    for (int off = 1; off < 128; off <<= 1) {
        int t = (tid < 128 && tid >= (unsigned)off) ? scn[tid - off] : 0;
        __syncthreads();
        if (tid < 128) scn[tid] += t;
        __syncthreads();
    }
    if (tid < 128) {
        int excl = scn[tid] - v;
        cur[tid] = excl;
        if (tid < nodes) ptr[node0 + tid] = base + excl;
    }
    if (b == nb - 1 && tid == 0) ptr[N] = Etot;
    __syncthreads();
    for (int i = tid; i < count; i += 256) {
        unsigned int p = bkt[base + i];
        int dloc = p >> 20;
        int s = (int)(p & 0xFFFFFu);
        int pos = base + atomicAdd(&cur[dloc], 1);
        csr_src[pos] = s;
        float4 a = *(const float4*)&es[s * 4];
        float4 bb = *(const float4*)&ed[(node0 + dloc) * 4];
        union { _Float16 h[4]; uint2 u; } ww;
        ww.h[0] = (_Float16)__expf(lrelu(a.x + bb.x));
        ww.h[1] = (_Float16)__expf(lrelu(a.y + bb.y));
        ww.h[2] = (_Float16)__expf(lrelu(a.z + bb.z));
        ww.h[3] = (_Float16)__expf(lrelu(a.w + bb.w));
        *(uint2*)&w1h[(size_t)pos * 4] = ww.u;
    }
}

// ---------------------------------------------------------------------------
// Aggregation layer 1 FUSED with GEMM2 + dots2. Gather layout is the proven
// R0 one (16 lanes/node x 8 channels, 4 nodes/wave, 16 nodes/block). The
// ELU'd h1e row is parked in LDS instead of round-tripping 12.8MB x2 through
// global; each thread then computes its node's 2 output channels of
// h2 = h1e @ W2 (bf16 quantized operands, fp32 accum — same quantization
// points as the deleted MFMA gemm2), plus the es2/ed2 dots via 16-lane
// shuffle reduce. Deletes one dispatch + h1e traffic entirely.
// LDS: hs 16x136x2 + w2l 128x36x2 = 13.6KB -> still wave-capped 8 blk/CU.
// ---------------------------------------------------------------------------
__global__ __launch_bounds__(256) void agg1_gemm2_kernel(
        const uint4* __restrict__ h1v, const _Float16* __restrict__ w1h,
        const int* __restrict__ csr, const int* __restrict__ ptr,
        const float* __restrict__ b1, const float* __restrict__ W2,
        const float* __restrict__ a_src2, const float* __restrict__ a_dst2,
        unsigned short* __restrict__ h2b, float* __restrict__ es2,
        float* __restrict__ ed2, int N) {
    __shared__ unsigned short hs[16][136];   // ELU'd h1e tile (16 nodes)
    __shared__ unsigned short w2l[128][36];  // bf16 W2 [k][c], padded row
    int tid = threadIdx.x;

    // stage W2 -> bf16 (same [k][c] layout as source; coalesced)
    for (int i = tid; i < 4096; i += 256) {
        int k = i >> 5, c = i & 31;
        w2l[k][c] = f2b(W2[i]);
    }

    int n = blockIdx.x * 16 + (tid >> 4);
    int node = tid >> 4;
    int cl = tid & 15;           // 16-B granule: channels 8cl..8cl+7
    int h = cl >> 2;             // head
    bool act = (n < N);
    int start = 0, end = 0;
    if (act) { start = ptr[n]; end = ptr[n + 1]; }
    float a0 = 0.f, a1 = 0.f, a2 = 0.f, a3 = 0.f;
    float a4 = 0.f, a5 = 0.f, a6 = 0.f, a7 = 0.f, ws = 0.f;
    int i = start;
    for (; i + 4 <= end; i += 4) {
        int s[4]; float v[4]; uint4 g[4];
#pragma unroll
        for (int k = 0; k < 4; k++) s[k] = csr[i + k];
#pragma unroll
        for (int k = 0; k < 4; k++) v[k] = (float)w1h[(size_t)(i + k) * 4 + h];
#pragma unroll
        for (int k = 0; k < 4; k++) g[k] = h1v[(s[k] << 4) + cl];
#pragma unroll
        for (int k = 0; k < 4; k++) {
            a0 += v[k] * b2f((unsigned short)(g[k].x & 0xffffu));
            a1 += v[k] * b2f((unsigned short)(g[k].x >> 16));
            a2 += v[k] * b2f((unsigned short)(g[k].y & 0xffffu));
            a3 += v[k] * b2f((unsigned short)(g[k].y >> 16));
            a4 += v[k] * b2f((unsigned short)(g[k].z & 0xffffu));
            a5 += v[k] * b2f((unsigned short)(g[k].z >> 16));
            a6 += v[k] * b2f((unsigned short)(g[k].w & 0xffffu));
            a7 += v[k] * b2f((unsigned short)(g[k].w >> 16));
            ws += v[k];
        }
    }
    for (; i < end; i++) {
        int s = csr[i];
        float v = (float)w1h[(size_t)i * 4 + h];
        uint4 g = h1v[(s << 4) + cl];
        a0 += v * b2f((unsigned short)(g.x & 0xffffu));
        a1 += v * b2f((unsigned short)(g.x >> 16));
        a2 += v * b2f((unsigned short)(g.y & 0xffffu));
        a3 += v * b2f((unsigned short)(g.y >> 16));
        a4 += v * b2f((unsigned short)(g.z & 0xffffu));
        a5 += v * b2f((unsigned short)(g.z >> 16));
        a6 += v * b2f((unsigned short)(g.w & 0xffffu));
        a7 += v * b2f((unsigned short)(g.w >> 16));
        ws += v;
    }
    if (act) {
        float r = 1.f / ws;
        float4 bb0 = ((const float4*)b1)[cl * 2];
        float4 bb1 = ((const float4*)b1)[cl * 2 + 1];
        float o0 = a0 * r + bb0.x;
        float o1 = a1 * r + bb0.y;
        float o2 = a2 * r + bb0.z;
        float o3 = a3 * r + bb0.w;
        float o4 = a4 * r + bb1.x;
        float o5 = a5 * r + bb1.y;
        float o6 = a6 * r + bb1.z;
        float o7 = a7 * r + bb1.w;
        o0 = o0 > 0.f ? o0 : __expf(o0) - 1.f;
        o1 = o1 > 0.f ? o1 : __expf(o1) - 1.f;
        o2 = o2 > 0.f ? o2 : __expf(o2) - 1.f;
        o3 = o3 > 0.f ? o3 : __expf(o3) - 1.f;
        o4 = o4 > 0.f ? o4 : __expf(o4) - 1.f;
        o5 = o5 > 0.f ? o5 : __expf(o5) - 1.f;
        o6 = o6 > 0.f ? o6 : __expf(o6) - 1.f;
        o7 = o7 > 0.f ? o7 : __expf(o7) - 1.f;
        uint4 outv;
        outv.x = (unsigned int)f2b(o0) | ((unsigned int)f2b(o1) << 16);
        outv.y = (unsigned int)f2b(o2) | ((unsigned int)f2b(o3) << 16);
        outv.z = (unsigned int)f2b(o4) | ((unsigned int)f2b(o5) << 16);
        outv.w = (unsigned int)f2b(o6) | ((unsigned int)f2b(o7) << 16);
        *(uint4*)&hs[node][cl * 8] = outv;   // park tile in LDS (no global)
    }
    __syncthreads();   // hs complete (all nodes) + w2l staged

    // fused gemm2: this thread computes h2[n][c2], h2[n][c2+1]
    if (act) {
        int c2 = cl * 2;
        float o0 = 0.f, o1 = 0.f;
#pragma unroll 4
        for (int k = 0; k < 128; k += 2) {
            unsigned int hu = *(const unsigned int*)&hs[node][k];   // broadcast
            float h0 = b2f((unsigned short)(hu & 0xffffu));
            float h1 = b2f((unsigned short)(hu >> 16));
            unsigned int w0 = *(const unsigned int*)&w2l[k][c2];
            unsigned int w1 = *(const unsigned int*)&w2l[k + 1][c2];
            o0 += h0 * b2f((unsigned short)(w0 & 0xffffu));
            o1 += h0 * b2f((unsigned short)(w0 >> 16));
            o0 += h1 * b2f((unsigned short)(w1 & 0xffffu));
            o1 += h1 * b2f((unsigned short)(w1 >> 16));
        }
        // quantize (same point as old gemm2's xs staging), write h2b
        unsigned short q0 = f2b(o0), q1 = f2b(o1);
        *(unsigned int*)&h2b[(size_t)n * 32 + c2] =
            (unsigned int)q0 | ((unsigned int)q1 << 16);
        // fused dots2 from quantized values (parity with old dots2)
        float vq0 = b2f(q0), vq1 = b2f(q1);
        float2 as = *(const float2*)&a_src2[c2];
        float2 ad = *(const float2*)&a_dst2[c2];
        float s = vq0 * as.x + vq1 * as.y;
        float d = vq0 * ad.x + vq1 * ad.y;
        s += __shfl_xor(s, 1);  d += __shfl_xor(d, 1);
        s += __shfl_xor(s, 2);  d += __shfl_xor(d, 2);
        s += __shfl_xor(s, 4);  d += __shfl_xor(d, 4);
        s += __shfl_xor(s, 8);  d += __shfl_xor(d, 8);
        if (cl == 0) { es2[n] = s; ed2[n] = d; }
    }
}

// ---------------------------------------------------------------------------
// Aggregation layer 2: R0-exact — 8 lanes/node x 4 channels, 8 nodes/wave,
// 32/block; unroll x8; inline exp weights.
// ---------------------------------------------------------------------------
__global__ __launch_bounds__(256) void agg2_kernel(
        const uint2* __restrict__ h2v, const float* __restrict__ es,
        const float* __restrict__ ed, const int* __restrict__ csr,
        const int* __restrict__ ptr, const float* __restrict__ b2,
        float* __restrict__ out, int N) {
    int tid = threadIdx.x;
    int n = blockIdx.x * 32 + (tid >> 3);
    if (n >= N) return;
    int cl = tid & 7;            // channels 4cl..4cl+3
    float edl = ed[n];
    int start = ptr[n], end = ptr[n + 1];
    float a0 = 0.f, a1 = 0.f, a2 = 0.f, a3 = 0.f, ws = 0.f;
    int i = start;
    for (; i + 8 <= end; i += 8) {
        int s[8]; float e[8]; uint2 g[8];
#pragma unroll
        for (int k = 0; k < 8; k++) s[k] = csr[i + k];
#pragma unroll
        for (int k = 0; k < 8; k++) e[k] = es[s[k]];
#pragma unroll
        for (int k = 0; k < 8; k++) g[k] = h2v[(s[k] << 3) + cl];
#pragma unroll
        for (int k = 0; k < 8; k++) {
            float v = __expf(lrelu(e[k] + edl));
            a0 += v * b2f((unsigned short)(g[k].x & 0xffffu));
            a1 += v * b2f((unsigned short)(g[k].x >> 16));
            a2 += v * b2f((unsigned short)(g[k].y & 0xffffu));
            a3 += v * b2f((unsigned short)(g[k].y >> 16));
            ws += v;
        }
    }
    for (; i < end; i++) {
        int s = csr[i];
        float v = __expf(lrelu(es[s] + edl));
        uint2 g = h2v[(s << 3) + cl];
        a0 += v * b2f((unsigned short)(g.x & 0xffffu));
        a1 += v * b2f((unsigned short)(g.x >> 16));
        a2 += v * b2f((unsigned short)(g.y & 0xffffu));
        a3 += v * b2f((unsigned short)(g.y >> 16));
        ws += v;
    }
    float r = 1.f / ws;
    float4 bb = ((const float4*)b2)[cl];
    float4 o;
    o.x = a0 * r + bb.x;
    o.y = a1 * r + bb.y;
    o.z = a2 * r + bb.z;
    o.w = a3 * r + bb.w;
    ((float4*)out)[(size_t)n * 8 + cl] = o;
}

// ---------------------------------------------------------------------------
extern "C" void kernel_launch(void* const* d_in, const int* in_sizes, int n_in,
                              void* d_out, int out_size, void* d_ws, size_t ws_size,
                              hipStream_t stream) {
    const float* x      = (const float*)d_in[0];
    const int*   ei     = (const int*)  d_in[1];
    const float* W1     = (const float*)d_in[2];
    const float* a_src1 = (const float*)d_in[3];
    const float* a_dst1 = (const float*)d_in[4];
    const float* b1     = (const float*)d_in[5];
    const float* W2     = (const float*)d_in[6];
    const float* a_src2 = (const float*)d_in[7];
    const float* a_dst2 = (const float*)d_in[8];
    const float* b2     = (const float*)d_in[9];
    float* outp = (float*)d_out;

    const int N = in_sizes[0] / 128;   // 50000
    const int E = in_sizes[1] / 2;     // 800000
    const int Etot = E + N;            // 850000

    const int* src = ei;
    const int* dst = ei + E;

    const int nb    = (N + 127) >> 7;                // 391 buckets
    const int chunk = (Etot + NBLK - 1) / NBLK;      // 1661
    const int M = nb * NBLK;                         // 200192 scan elements
    const int nbA = (M + 1023) / 1024;               // 196

    // workspace layout (bytes); ~48.8 MB (h1e slot now unused)
    char* w = (char*)d_ws;
    unsigned short* h1b = (unsigned short*)(w + 0);          // 12,800,000
    unsigned short* h2b = (unsigned short*)(w + 25600000);   //  3,200,000
    float* es1  = (float*)(w + 28800000);                    //    800,000
    float* ed1  = (float*)(w + 29600000);                    //    800,000
    float* es2  = (float*)(w + 30400000);                    //    200,000
    float* ed2  = (float*)(w + 30600000);                    //    200,000
    int*   ptr  = (int*)  (w + 30800000);                    //    200,064
    int*   bsum = (int*)  (w + 31000064);                    //      1,024
    int*   cnt  = (int*)  (w + 31001088);                    //    800,768
    int*   csr_src = (int*)(w + 31801856);                   //  3,400,000
    unsigned int* bkt = (unsigned int*)(w + 35201856);       //  3,400,000 (packed)
    _Float16* w1h = (_Float16*)(w + 42001856);               //  6,800,000 -> 48,801,856

    // --- Layer-1 GEMM + fused dots1 + fused hist ---
    gemm1_mfma_kernel<<<(N + 63) / 64, 256, 0, stream>>>(x, W1, a_src1, a_dst1,
                                                         h1b, es1, ed1, N,
                                                         dst, E, Etot, nb, chunk,
                                                         cnt);

    // --- CSR build: scanA -> partition -> finalize ---
    scanA_kernel<<<nbA, 1024, 0, stream>>>(cnt, bsum, M);
    partition_kernel<<<NBLK, 256, 0, stream>>>(src, dst, E, Etot, nb, chunk, nbA,
                                               cnt, bsum, bkt);
    finalize_kernel<<<nb, 256, 0, stream>>>(bkt, cnt, bsum, nb, nbA, es1, ed1,
                                            ptr, csr_src, w1h, N, Etot);

    // --- Layer 1 aggregate FUSED with layer-2 GEMM + dots2 ---
    agg1_gemm2_kernel<<<(N + 15) / 16, 256, 0, stream>>>((const uint4*)h1b, w1h,
                                                         csr_src, ptr, b1, W2,
                                                         a_src2, a_dst2,
                                                         h2b, es2, ed2, N);

    // --- Layer 2 aggregate with inline weights ---
    agg2_kernel<<<(N + 31) / 32, 256, 0, stream>>>((const uint2*)h2b, es2, ed2,
                                                   csr_src, ptr, b2, outp, N);
}

// Round 7
// 191.283 us; speedup vs baseline: 1.2972x; 1.0350x over previous
//
#include <hip/hip_runtime.h>
#include <hip/hip_bf16.h>

#define LRELU_SLOPE 0.2f
#define NB_SHIFT 7          // 128 dst-nodes per bucket
#define NBLK 512            // hist/partition parallel chunks

typedef __attribute__((ext_vector_type(8))) short short8;
typedef __attribute__((ext_vector_type(4))) float float4v;

// bf16 <-> fp32 helpers (raw ushort storage)
__device__ inline float b2f(unsigned short u) {
    union { unsigned int i; float f; } v; v.i = ((unsigned int)u) << 16; return v.f;
}
__device__ inline unsigned short f2b(float f) {
    union { float f; unsigned int i; } v; v.f = f;
    unsigned int x = v.i;
    unsigned int r = x + 0x7fffu + ((x >> 16) & 1u);   // round-to-nearest-even
    return (unsigned short)(r >> 16);
}
__device__ inline float lrelu(float x) { return x > 0.f ? x : LRELU_SLOPE * x; }

// ---------------------------------------------------------------------------
// GEMM1 (MFMA bf16) + fused dots1 + fused CSR hist (blocks < NBLK).
// R5 form (vectorized h1b write; LDS-privatized hist — R4 measured global
// deg atomics at +25MB write traffic / cross-XCD line ping-pong).
// ---------------------------------------------------------------------------
__global__ __launch_bounds__(256) void gemm1_mfma_kernel(
        const float* __restrict__ x, const float* __restrict__ W1,
        const float* __restrict__ a_src, const float* __restrict__ a_dst,
        unsigned short* __restrict__ h1b, float* __restrict__ es,
        float* __restrict__ ed, int N,
        const int* __restrict__ dst, int E, int Etot, int nb, int chunk,
        int* __restrict__ cnt) {
    __shared__ unsigned short xs[64][136];
    __shared__ unsigned short wt[128][136];
    int tid = threadIdx.x;
    int n0 = blockIdx.x * 64;

    for (int i = tid; i < 128 * 128; i += 256) {
        int k = i >> 7, n = i & 127;
        wt[n][k] = f2b(W1[i]);
    }
    {
        int rows = N - n0; if (rows > 64) rows = 64;
        const float4* xv = (const float4*)(x + (size_t)n0 * 128);
        int lim = rows * 32;                 // float4 count
        for (int i = tid; i < lim; i += 256) {
            float4 v = xv[i];
            int r = i >> 5, c4 = (i & 31) << 2;
            uint2 p;
            p.x = (unsigned int)f2b(v.x) | ((unsigned int)f2b(v.y) << 16);
            p.y = (unsigned int)f2b(v.z) | ((unsigned int)f2b(v.w) << 16);
            *(uint2*)&xs[r][c4] = p;
        }
    }
    __syncthreads();

    int wave = tid >> 6;
    int lane = tid & 63;
    int lrow = lane & 15;
    int quad = lane >> 4;

    short8 afr[4];
#pragma unroll
    for (int kc = 0; kc < 4; kc++)
        afr[kc] = *(const short8*)&xs[wave * 16 + lrow][kc * 32 + quad * 8];
    __syncthreads();   // all waves' A-fragment reads done before xs is reused

#pragma unroll
    for (int ct = 0; ct < 8; ct++) {
        float4v acc = {0.f, 0.f, 0.f, 0.f};
#pragma unroll
        for (int kc = 0; kc < 4; kc++) {
            short8 bfr = *(const short8*)&wt[ct * 16 + lrow][kc * 32 + quad * 8];
            acc = __builtin_amdgcn_mfma_f32_16x16x32_bf16(afr[kc], bfr, acc, 0, 0, 0);
        }
#pragma unroll
        for (int r = 0; r < 4; r++) {
            int lr = wave * 16 + quad * 4 + r;
            xs[lr][ct * 16 + lrow] = f2b(acc[r]);  // stage result tile only
        }
    }
    __syncthreads();   // xs result tile ready; wt reads done (reused below)

    {   // vectorized h1b write: rows*16 uint4 (16B/lane, 1KB/wave-instr)
        int rows = N - n0; if (rows > 64) rows = 64;
        int lim4 = rows * 16;
        for (int i = tid; i < lim4; i += 256) {
            int r = i >> 4, c8 = i & 15;
            *(uint4*)&h1b[(size_t)(n0 + r) * 128 + c8 * 8] =
                *(const uint4*)&xs[r][c8 * 8];
        }
    }

    // fused dots1: thread = (row, head); 32-channel dot per head
    int row = tid >> 2, h = tid & 3;
    int rg = n0 + row;
    if (rg < N) {
        const float* ap = a_src + h * 32;
        const float* bp = a_dst + h * 32;
        float s = 0.f, d = 0.f;
#pragma unroll
        for (int c2 = 0; c2 < 16; c2++) {
            unsigned int u = *(const unsigned int*)&xs[row][h * 32 + 2 * c2];
            float v0 = b2f((unsigned short)(u & 0xffffu));
            float v1 = b2f((unsigned short)(u >> 16));
            float2 a = *(const float2*)&ap[2 * c2];
            float2 b = *(const float2*)&bp[2 * c2];
            s += v0 * a.x + v1 * a.y;
            d += v0 * b.x + v1 * b.y;
        }
        es[rg * 4 + h] = s;
        ed[rg * 4 + h] = d;
    }

    // fused CSR histogram (reuses wt LDS; all threads hit the barriers)
    int* histm = (int*)&wt[0][0];
    int blk = blockIdx.x;
    if (blk < NBLK)
        for (int i = tid; i < nb; i += 256) histm[i] = 0;
    __syncthreads();
    if (blk < NBLK) {
        int lo = blk * chunk;
        int hi = lo + chunk; if (hi > Etot) hi = Etot;
        for (int i = lo + tid; i < hi; i += 256) {
            int d = (i < E) ? dst[i] : (i - E);
            atomicAdd(&histm[d >> NB_SHIFT], 1);
        }
    }
    __syncthreads();
    if (blk < NBLK)
        for (int b = tid; b < nb; b += 256)
            cnt[b * NBLK + blk] = histm[b];
}

// ---------------------------------------------------------------------------
// scanA: tile-exclusive scan of cnt; bsum[tile] = inclusive tile total.
// ---------------------------------------------------------------------------
__global__ __launch_bounds__(1024) void scanA_kernel(int* cnt, int* bsum, int M) {
    __shared__ int tile[1024];
    int i = blockIdx.x * 1024 + threadIdx.x;
    int v = (i < M) ? cnt[i] : 0;
    tile[threadIdx.x] = v;
    __syncthreads();
    for (int off = 1; off < 1024; off <<= 1) {
        int t = (threadIdx.x >= (unsigned)off) ? tile[threadIdx.x - off] : 0;
        __syncthreads();
        tile[threadIdx.x] += t;
        __syncthreads();
    }
    int incl = tile[threadIdx.x];
    if (i < M) cnt[i] = incl - v;
    if (threadIdx.x == 1023) bsum[blockIdx.x] = incl;
}

// Inline 256-slot exclusive scan of bsum[0..nbA) into boffl.
__device__ inline void boff_scan(const int* __restrict__ bsum, int nbA,
                                 int* boffl, int tid) {
    int v = (tid < nbA) ? bsum[tid] : 0;
    boffl[tid] = v;
    __syncthreads();
    for (int off = 1; off < 256; off <<= 1) {
        int t = (tid >= off) ? boffl[tid - off] : 0;
        __syncthreads();
        boffl[tid] += t;
        __syncthreads();
    }
    int excl = boffl[tid] - v;
    __syncthreads();
    boffl[tid] = excl;
    __syncthreads();
}

// ---------------------------------------------------------------------------
// CSR build, pass 2: partition edges into bucket array (LDS atomics only).
// bkt packed: (dloc<<20)|src.
// ---------------------------------------------------------------------------
__global__ __launch_bounds__(256) void partition_kernel(
        const int* __restrict__ src, const int* __restrict__ dst,
        int E, int Etot, int nb, int chunk, int nbA,
        const int* __restrict__ cnt, const int* __restrict__ bsum,
        unsigned int* __restrict__ bkt) {
    __shared__ int cur[512];
    __shared__ int boffl[256];
    int tid = threadIdx.x;
    boff_scan(bsum, nbA, boffl, tid);
    int blk = blockIdx.x;
    for (int b = tid; b < nb; b += 256) {
        int idx = b * NBLK + blk;
        cur[b] = cnt[idx] + boffl[idx >> 10];
    }
    __syncthreads();
    int lo = blk * chunk;
    int hi = lo + chunk; if (hi > Etot) hi = Etot;
    for (int i = lo + tid; i < hi; i += 256) {
        int s, d;
        if (i < E) { s = src[i]; d = dst[i]; }
        else       { s = d = i - E; }
        int pos = atomicAdd(&cur[d >> NB_SHIFT], 1);
        bkt[pos] = ((unsigned int)(d & 127) << 20) | (unsigned int)s;
    }
}

// ---------------------------------------------------------------------------
// CSR build, pass 3 (one block per bucket): degree count -> LDS scan -> ptr;
// place src indices at final CSR positions; fold in fp16 layer-1 edge weights.
// ---------------------------------------------------------------------------
__global__ __launch_bounds__(256) void finalize_kernel(
        const unsigned int* __restrict__ bkt, const int* __restrict__ cnt,
        const int* __restrict__ bsum, int nb, int nbA,
        const float* __restrict__ es, const float* __restrict__ ed,
        int* __restrict__ ptr, int* __restrict__ csr_src,
        _Float16* __restrict__ w1h, int N, int Etot) {
    __shared__ int deg[128];
    __shared__ int scn[128];
    __shared__ int cur[128];
    __shared__ int boffl[256];
    int tid = threadIdx.x;
    boff_scan(bsum, nbA, boffl, tid);
    int b = blockIdx.x;
    int idx0 = b * NBLK;
    int base = cnt[idx0] + boffl[idx0 >> 10];
    int nextbase;
    if (b + 1 < nb) {
        int idx1 = (b + 1) * NBLK;
        nextbase = cnt[idx1] + boffl[idx1 >> 10];
    } else nextbase = Etot;
    int count = nextbase - base;
    int node0 = b << NB_SHIFT;
    int nodes = N - node0; if (nodes > 128) nodes = 128;

    if (tid < 128) deg[tid] = 0;
    __syncthreads();
    for (int i = tid; i < count; i += 256)
        atomicAdd(&deg[bkt[base + i] >> 20], 1);
    __syncthreads();
    int v = (tid < 128) ? deg[tid] : 0;
    if (tid < 128) scn[tid] = v;
    __syncthreads();
    for (int off = 1; off < 128; off <<= 1) {
        int t = (tid < 128 && tid >= (unsigned)off) ? scn[tid - off] : 0;
        __syncthreads();
        if (tid < 128) scn[tid] += t;
        __syncthreads();
    }
    if (tid < 128) {
        int excl = scn[tid] - v;
        cur[tid] = excl;
        if (tid < nodes) ptr[node0 + tid] = base + excl;
    }
    if (b == nb - 1 && tid == 0) ptr[N] = Etot;
    __syncthreads();
    for (int i = tid; i < count; i += 256) {
        unsigned int p = bkt[base + i];
        int dloc = p >> 20;
        int s = (int)(p & 0xFFFFFu);
        int pos = base + atomicAdd(&cur[dloc], 1);
        csr_src[pos] = s;
        float4 a = *(const float4*)&es[s * 4];
        float4 bb = *(const float4*)&ed[(node0 + dloc) * 4];
        union { _Float16 h[4]; uint2 u; } ww;
        ww.h[0] = (_Float16)__expf(lrelu(a.x + bb.x));
        ww.h[1] = (_Float16)__expf(lrelu(a.y + bb.y));
        ww.h[2] = (_Float16)__expf(lrelu(a.z + bb.z));
        ww.h[3] = (_Float16)__expf(lrelu(a.w + bb.w));
        *(uint2*)&w1h[(size_t)pos * 4] = ww.u;
    }
}

// ---------------------------------------------------------------------------
// Aggregation layer 1 FUSED with GEMM2 + dots2 (R6 structure, R7 tail fix).
// Gather layout: proven R0 (16 lanes/node x 8 channels, 4 nodes/wave,
// 16 nodes/block). ELU'd tile parked in hs LDS (no h1e global roundtrip).
// R7: the gemm2 tail is MFMA again — the 16x128 hs tile is exactly one
// 16x16x32 A-tile; wave 0 computes h2 = hs @ W2 with 8 MFMAs (identical
// fragment code to the deleted gemm2 kernel; hs has the same 136-short row
// stride as its xs). Replaces the R6 scalar tail (~192 ds_read_b32 + ~620
// VALU per thread x 256 threads — measured as the bulk of VALUBusy=58%).
// dots2 via 16-lane shuffle reduce from the quantized accumulators.
// ---------------------------------------------------------------------------
__global__ __launch_bounds__(256) void agg1_gemm2_kernel(
        const uint4* __restrict__ h1v, const _Float16* __restrict__ w1h,
        const int* __restrict__ csr, const int* __restrict__ ptr,
        const float* __restrict__ b1, const float* __restrict__ W2,
        const float* __restrict__ a_src2, const float* __restrict__ a_dst2,
        unsigned short* __restrict__ h2b, float* __restrict__ es2,
        float* __restrict__ ed2, int N) {
    __shared__ unsigned short hs[16][136];   // ELU'd h1e tile (16 nodes)
    __shared__ unsigned short w2l[32][136];  // bf16 W2^T: w2l[outcol][k]
    int tid = threadIdx.x;

    // stage W2 -> bf16 (old gemm2 layout: row = out col, 128 k per row)
    for (int i = tid; i < 4096; i += 256) {
        int k = i >> 5, n = i & 31;
        w2l[n][k] = f2b(W2[i]);
    }

    int n = blockIdx.x * 16 + (tid >> 4);
    int node = tid >> 4;
    int cl = tid & 15;           // 16-B granule: channels 8cl..8cl+7
    int h = cl >> 2;             // head
    bool act = (n < N);
    int start = 0, end = 0;
    if (act) { start = ptr[n]; end = ptr[n + 1]; }
    float a0 = 0.f, a1 = 0.f, a2 = 0.f, a3 = 0.f;
    float a4 = 0.f, a5 = 0.f, a6 = 0.f, a7 = 0.f, ws = 0.f;
    int i = start;
    for (; i + 4 <= end; i += 4) {
        int s[4]; float v[4]; uint4 g[4];
#pragma unroll
        for (int k = 0; k < 4; k++) s[k] = csr[i + k];
#pragma unroll
        for (int k = 0; k < 4; k++) v[k] = (float)w1h[(size_t)(i + k) * 4 + h];
#pragma unroll
        for (int k = 0; k < 4; k++) g[k] = h1v[(s[k] << 4) + cl];
#pragma unroll
        for (int k = 0; k < 4; k++) {
            a0 += v[k] * b2f((unsigned short)(g[k].x & 0xffffu));
            a1 += v[k] * b2f((unsigned short)(g[k].x >> 16));
            a2 += v[k] * b2f((unsigned short)(g[k].y & 0xffffu));
            a3 += v[k] * b2f((unsigned short)(g[k].y >> 16));
            a4 += v[k] * b2f((unsigned short)(g[k].z & 0xffffu));
            a5 += v[k] * b2f((unsigned short)(g[k].z >> 16));
            a6 += v[k] * b2f((unsigned short)(g[k].w & 0xffffu));
            a7 += v[k] * b2f((unsigned short)(g[k].w >> 16));
            ws += v[k];
        }
    }
    for (; i < end; i++) {
        int s = csr[i];
        float v = (float)w1h[(size_t)i * 4 + h];
        uint4 g = h1v[(s << 4) + cl];
        a0 += v * b2f((unsigned short)(g.x & 0xffffu));
        a1 += v * b2f((unsigned short)(g.x >> 16));
        a2 += v * b2f((unsigned short)(g.y & 0xffffu));
        a3 += v * b2f((unsigned short)(g.y >> 16));
        a4 += v * b2f((unsigned short)(g.z & 0xffffu));
        a5 += v * b2f((unsigned short)(g.z >> 16));
        a6 += v * b2f((unsigned short)(g.w & 0xffffu));
        a7 += v * b2f((unsigned short)(g.w >> 16));
        ws += v;
    }
    if (act) {
        float r = 1.f / ws;
        float4 bb0 = ((const float4*)b1)[cl * 2];
        float4 bb1 = ((const float4*)b1)[cl * 2 + 1];
        float o0 = a0 * r + bb0.x;
        float o1 = a1 * r + bb0.y;
        float o2 = a2 * r + bb0.z;
        float o3 = a3 * r + bb0.w;
        float o4 = a4 * r + bb1.x;
        float o5 = a5 * r + bb1.y;
        float o6 = a6 * r + bb1.z;
        float o7 = a7 * r + bb1.w;
        o0 = o0 > 0.f ? o0 : __expf(o0) - 1.f;
        o1 = o1 > 0.f ? o1 : __expf(o1) - 1.f;
        o2 = o2 > 0.f ? o2 : __expf(o2) - 1.f;
        o3 = o3 > 0.f ? o3 : __expf(o3) - 1.f;
        o4 = o4 > 0.f ? o4 : __expf(o4) - 1.f;
        o5 = o5 > 0.f ? o5 : __expf(o5) - 1.f;
        o6 = o6 > 0.f ? o6 : __expf(o6) - 1.f;
        o7 = o7 > 0.f ? o7 : __expf(o7) - 1.f;
        uint4 outv;
        outv.x = (unsigned int)f2b(o0) | ((unsigned int)f2b(o1) << 16);
        outv.y = (unsigned int)f2b(o2) | ((unsigned int)f2b(o3) << 16);
        outv.z = (unsigned int)f2b(o4) | ((unsigned int)f2b(o5) << 16);
        outv.w = (unsigned int)f2b(o6) | ((unsigned int)f2b(o7) << 16);
        *(uint4*)&hs[node][cl * 8] = outv;   // park tile in LDS (no global)
    } else {
        uint4 z = make_uint4(0u, 0u, 0u, 0u); // clean operands for tail MFMA
        *(uint4*)&hs[node][cl * 8] = z;
    }
    __syncthreads();   // hs complete (all 16 rows) + w2l staged

    // fused gemm2 tail: wave 0 only, 8 MFMAs for the whole 16x32 output tile
    if (tid < 64) {
        int lane = tid;
        int lrow = lane & 15;
        int quad = lane >> 4;
        short8 afr[4];
#pragma unroll
        for (int kc = 0; kc < 4; kc++)
            afr[kc] = *(const short8*)&hs[lrow][kc * 32 + quad * 8];
        float4v acc0 = {0.f, 0.f, 0.f, 0.f};
        float4v acc1 = {0.f, 0.f, 0.f, 0.f};
#pragma unroll
        for (int kc = 0; kc < 4; kc++) {
            short8 b0 = *(const short8*)&w2l[lrow][kc * 32 + quad * 8];
            short8 b1 = *(const short8*)&w2l[16 + lrow][kc * 32 + quad * 8];
            acc0 = __builtin_amdgcn_mfma_f32_16x16x32_bf16(afr[kc], b0, acc0, 0, 0, 0);
            acc1 = __builtin_amdgcn_mfma_f32_16x16x32_bf16(afr[kc], b1, acc1, 0, 0, 0);
        }
        int n0g = blockIdx.x * 16;
        float as_lo = a_src2[lrow], as_hi = a_src2[16 + lrow];
        float ad_lo = a_dst2[lrow], ad_hi = a_dst2[16 + lrow];
#pragma unroll
        for (int r = 0; r < 4; r++) {
            int nn = n0g + quad * 4 + r;
            unsigned short q0 = f2b(acc0[r]);
            unsigned short q1 = f2b(acc1[r]);
            float v0 = b2f(q0), v1 = b2f(q1);
            float s = v0 * as_lo + v1 * as_hi;
            float d = v0 * ad_lo + v1 * ad_hi;
            s += __shfl_xor(s, 1); d += __shfl_xor(d, 1);
            s += __shfl_xor(s, 2); d += __shfl_xor(d, 2);
            s += __shfl_xor(s, 4); d += __shfl_xor(d, 4);
            s += __shfl_xor(s, 8); d += __shfl_xor(d, 8);
            if (nn < N) {
                h2b[(size_t)nn * 32 + lrow] = q0;
                h2b[(size_t)nn * 32 + 16 + lrow] = q1;
                if (lrow == 0) { es2[nn] = s; ed2[nn] = d; }
            }
        }
    }
}

// ---------------------------------------------------------------------------
// Aggregation layer 2: R0-exact — 8 lanes/node x 4 channels, 8 nodes/wave,
// 32/block; unroll x8; inline exp weights.
// ---------------------------------------------------------------------------
__global__ __launch_bounds__(256) void agg2_kernel(
        const uint2* __restrict__ h2v, const float* __restrict__ es,
        const float* __restrict__ ed, const int* __restrict__ csr,
        const int* __restrict__ ptr, const float* __restrict__ b2,
        float* __restrict__ out, int N) {
    int tid = threadIdx.x;
    int n = blockIdx.x * 32 + (tid >> 3);
    if (n >= N) return;
    int cl = tid & 7;            // channels 4cl..4cl+3
    float edl = ed[n];
    int start = ptr[n], end = ptr[n + 1];
    float a0 = 0.f, a1 = 0.f, a2 = 0.f, a3 = 0.f, ws = 0.f;
    int i = start;
    for (; i + 8 <= end; i += 8) {
        int s[8]; float e[8]; uint2 g[8];
#pragma unroll
        for (int k = 0; k < 8; k++) s[k] = csr[i + k];
#pragma unroll
        for (int k = 0; k < 8; k++) e[k] = es[s[k]];
#pragma unroll
        for (int k = 0; k < 8; k++) g[k] = h2v[(s[k] << 3) + cl];
#pragma unroll
        for (int k = 0; k < 8; k++) {
            float v = __expf(lrelu(e[k] + edl));
            a0 += v * b2f((unsigned short)(g[k].x & 0xffffu));
            a1 += v * b2f((unsigned short)(g[k].x >> 16));
            a2 += v * b2f((unsigned short)(g[k].y & 0xffffu));
            a3 += v * b2f((unsigned short)(g[k].y >> 16));
            ws += v;
        }
    }
    for (; i < end; i++) {
        int s = csr[i];
        float v = __expf(lrelu(es[s] + edl));
        uint2 g = h2v[(s << 3) + cl];
        a0 += v * b2f((unsigned short)(g.x & 0xffffu));
        a1 += v * b2f((unsigned short)(g.x >> 16));
        a2 += v * b2f((unsigned short)(g.y & 0xffffu));
        a3 += v * b2f((unsigned short)(g.y >> 16));
        ws += v;
    }
    float r = 1.f / ws;
    float4 bb = ((const float4*)b2)[cl];
    float4 o;
    o.x = a0 * r + bb.x;
    o.y = a1 * r + bb.y;
    o.z = a2 * r + bb.z;
    o.w = a3 * r + bb.w;
    ((float4*)out)[(size_t)n * 8 + cl] = o;
}

// ---------------------------------------------------------------------------
extern "C" void kernel_launch(void* const* d_in, const int* in_sizes, int n_in,
                              void* d_out, int out_size, void* d_ws, size_t ws_size,
                              hipStream_t stream) {
    const float* x      = (const float*)d_in[0];
    const int*   ei     = (const int*)  d_in[1];
    const float* W1     = (const float*)d_in[2];
    const float* a_src1 = (const float*)d_in[3];
    const float* a_dst1 = (const float*)d_in[4];
    const float* b1     = (const float*)d_in[5];
    const float* W2     = (const float*)d_in[6];
    const float* a_src2 = (const float*)d_in[7];
    const float* a_dst2 = (const float*)d_in[8];
    const float* b2     = (const float*)d_in[9];
    float* outp = (float*)d_out;

    const int N = in_sizes[0] / 128;   // 50000
    const int E = in_sizes[1] / 2;     // 800000
    const int Etot = E + N;            // 850000

    const int* src = ei;
    const int* dst = ei + E;

    const int nb    = (N + 127) >> 7;                // 391 buckets
    const int chunk = (Etot + NBLK - 1) / NBLK;      // 1661
    const int M = nb * NBLK;                         // 200192 scan elements
    const int nbA = (M + 1023) / 1024;               // 196

    // workspace layout (bytes); ~48.8 MB (h1e slot unused since R6)
    char* w = (char*)d_ws;
    unsigned short* h1b = (unsigned short*)(w + 0);          // 12,800,000
    unsigned short* h2b = (unsigned short*)(w + 25600000);   //  3,200,000
    float* es1  = (float*)(w + 28800000);                    //    800,000
    float* ed1  = (float*)(w + 29600000);                    //    800,000
    float* es2  = (float*)(w + 30400000);                    //    200,000
    float* ed2  = (float*)(w + 30600000);                    //    200,000
    int*   ptr  = (int*)  (w + 30800000);                    //    200,064
    int*   bsum = (int*)  (w + 31000064);                    //      1,024
    int*   cnt  = (int*)  (w + 31001088);                    //    800,768
    int*   csr_src = (int*)(w + 31801856);                   //  3,400,000
    unsigned int* bkt = (unsigned int*)(w + 35201856);       //  3,400,000 (packed)
    _Float16* w1h = (_Float16*)(w + 42001856);               //  6,800,000 -> 48,801,856

    // --- Layer-1 GEMM + fused dots1 + fused hist ---
    gemm1_mfma_kernel<<<(N + 63) / 64, 256, 0, stream>>>(x, W1, a_src1, a_dst1,
                                                         h1b, es1, ed1, N,
                                                         dst, E, Etot, nb, chunk,
                                                         cnt);

    // --- CSR build: scanA -> partition -> finalize ---
    scanA_kernel<<<nbA, 1024, 0, stream>>>(cnt, bsum, M);
    partition_kernel<<<NBLK, 256, 0, stream>>>(src, dst, E, Etot, nb, chunk, nbA,
                                               cnt, bsum, bkt);
    finalize_kernel<<<nb, 256, 0, stream>>>(bkt, cnt, bsum, nb, nbA, es1, ed1,
                                            ptr, csr_src, w1h, N, Etot);

    // --- Layer 1 aggregate FUSED with layer-2 GEMM (MFMA tail) + dots2 ---
    agg1_gemm2_kernel<<<(N + 15) / 16, 256, 0, stream>>>((const uint4*)h1b, w1h,
                                                         csr_src, ptr, b1, W2,
                                                         a_src2, a_dst2,
                                                         h2b, es2, ed2, N);

    // --- Layer 2 aggregate with inline weights ---
    agg2_kernel<<<(N + 31) / 32, 256, 0, stream>>>((const uint2*)h2b, es2, ed2,
                                                   csr_src, ptr, b2, outp, N);
}